// Round 5
// baseline (982.488 us; speedup 1.0000x reference)
//
#include <hip/hip_runtime.h>
#include <stdint.h>

#define DEV __device__ __forceinline__

typedef __attribute__((ext_vector_type(8))) short short8;
typedef __attribute__((ext_vector_type(8))) __bf16 bf16x8;
typedef __attribute__((ext_vector_type(4))) float f32x4;
typedef __attribute__((ext_vector_type(16))) float f32x16;

DEV unsigned short f2bf(float f) {
  union { float f; unsigned int u; } v; v.f = f;
  unsigned int r = v.u + 0x7fffu + ((v.u >> 16) & 1u);
  return (unsigned short)(r >> 16);
}
DEV float bf2f(unsigned short h) {
  union { unsigned int u; float f; } v; v.u = ((unsigned int)h) << 16;
  return v.f;
}
DEV f32x4 mfma16(short8 a, short8 b, f32x4 c) {
  return __builtin_amdgcn_mfma_f32_16x16x32_bf16(
      __builtin_bit_cast(bf16x8, a), __builtin_bit_cast(bf16x8, b), c, 0, 0, 0);
}
DEV f32x16 mfma32(short8 a, short8 b, f32x16 c) {
  return __builtin_amdgcn_mfma_f32_32x32x16_bf16(
      __builtin_bit_cast(bf16x8, a), __builtin_bit_cast(bf16x8, b), c, 0, 0, 0);
}
DEV void gload_lds16(const void* g, void* lds) {
  __builtin_amdgcn_global_load_lds(
      (const __attribute__((address_space(1))) void*)g,
      (__attribute__((address_space(3))) void*)lds, 16, 0, 0);
}

struct MArgs {
  const float* src[7];
  unsigned short* dst[7];
  int n[7];
  int sidx[7];
};

// ---------------- abs-mean partial (all matrices, one launch) ----------------
__global__ __launch_bounds__(256) void absmean_partial_multi(
    MArgs a, float* __restrict__ partial) {
  const int m = blockIdx.y;
  const float4* w4 = (const float4*)a.src[m];
  const int n4 = a.n[m] >> 2;
  float s = 0.f;
  for (int i = blockIdx.x * 256 + threadIdx.x; i < n4; i += 1024 * 256) {
    float4 v = w4[i];
    s += fabsf(v.x) + fabsf(v.y) + fabsf(v.z) + fabsf(v.w);
  }
#pragma unroll
  for (int mm = 1; mm < 64; mm <<= 1) s += __shfl_xor(s, mm);
  __shared__ float red[4];
  if ((threadIdx.x & 63) == 0) red[threadIdx.x >> 6] = s;
  __syncthreads();
  if (threadIdx.x == 0)
    partial[m * 1024 + blockIdx.x] = red[0] + red[1] + red[2] + red[3];
}

__global__ __launch_bounds__(256) void absmean_final(
    const float* __restrict__ partial, float* __restrict__ scales) {
  __shared__ double red[256];
  const int m = blockIdx.x;
  double s = 0.0;
  for (int i = threadIdx.x; i < 1024; i += 256) s += (double)partial[m * 1024 + i];
  red[threadIdx.x] = s;
  __syncthreads();
  for (int t = 128; t > 0; t >>= 1) {
    if (threadIdx.x < t) red[threadIdx.x] += red[threadIdx.x + t];
    __syncthreads();
  }
  if (threadIdx.x == 0) {
    const long long cnt = (m < 4) ? 4194304ll : 16777216ll;
    scales[m] = (float)(red[0] / (double)cnt);
  }
}

// ---------------- ternary quantize -> bf16 (batched) ----------------
__global__ __launch_bounds__(256) void quantize_multi(
    MArgs a, const float* __restrict__ scales) {
  const int m = blockIdx.y;
  const float sc = scales[a.sidx[m]];
  const float inv = 1.f / (sc + 1e-5f);
  const float4* src = (const float4*)a.src[m];
  ushort4* dst = (ushort4*)a.dst[m];
  const int n4 = a.n[m] >> 2;
  for (int i = blockIdx.x * 256 + threadIdx.x; i < n4; i += 2048 * 256) {
    float4 v = src[i];
    ushort4 o;
    o.x = f2bf(fminf(fmaxf(rintf(v.x * inv), -1.f), 1.f) * sc);
    o.y = f2bf(fminf(fmaxf(rintf(v.y * inv), -1.f), 1.f) * sc);
    o.z = f2bf(fminf(fmaxf(rintf(v.z * inv), -1.f), 1.f) * sc);
    o.w = f2bf(fminf(fmaxf(rintf(v.w * inv), -1.f), 1.f) * sc);
    dst[i] = o;
  }
}

// ---------------- RMSNorm (f32 in -> bf16 out) ----------------
__global__ __launch_bounds__(256) void rmsnorm_k(
    const float* __restrict__ x, const float* __restrict__ wt,
    unsigned short* __restrict__ out) {
  const long long t = blockIdx.x;
  const float* xr = x + t * 2048;
  const int i0 = threadIdx.x * 8;
  float4 a = *(const float4*)(xr + i0);
  float4 b = *(const float4*)(xr + i0 + 4);
  float ss = a.x * a.x + a.y * a.y + a.z * a.z + a.w * a.w +
             b.x * b.x + b.y * b.y + b.z * b.z + b.w * b.w;
#pragma unroll
  for (int m = 1; m < 64; m <<= 1) ss += __shfl_xor(ss, m);
  __shared__ float red[4];
  if ((threadIdx.x & 63) == 0) red[threadIdx.x >> 6] = ss;
  __syncthreads();
  float tot = red[0] + red[1] + red[2] + red[3];
  float rs = rsqrtf(tot * (1.f / 2048.f) + 1e-5f);
  float4 wa = *(const float4*)(wt + i0);
  float4 wb = *(const float4*)(wt + i0 + 4);
  ushort4 o1, o2;
  o1.x = f2bf(a.x * wa.x * rs); o1.y = f2bf(a.y * wa.y * rs);
  o1.z = f2bf(a.z * wa.z * rs); o1.w = f2bf(a.w * wa.w * rs);
  o2.x = f2bf(b.x * wb.x * rs); o2.y = f2bf(b.y * wb.y * rs);
  o2.z = f2bf(b.z * wb.z * rs); o2.w = f2bf(b.w * wb.w * rs);
  *(ushort4*)(out + t * 2048 + i0) = o1;
  *(ushort4*)(out + t * 2048 + i0 + 4) = o2;
}

// ---------------- RoPE + V transpose ----------------
__global__ __launch_bounds__(256) void rope_k(
    const unsigned short* __restrict__ qkv, const float* __restrict__ cosT,
    const float* __restrict__ sinT, unsigned short* __restrict__ qr,
    unsigned short* __restrict__ kr, unsigned short* __restrict__ vt) {
  const long long gid = (long long)blockIdx.x * 256 + threadIdx.x;
  const int t = (int)(gid >> 10);
  const int r = (int)(gid & 1023);
  const int h = r >> 6, d = r & 63;
  const int s = t & 2047, b = t >> 11;
  const unsigned short* row = qkv + (long long)t * 6144;
  const float c = cosT[s * 128 + d], sn = sinT[s * 128 + d];
  const int col = h * 128 + d;
  const float SC = 0.08838834764831845f;  // 1/sqrt(128)
  float q1 = bf2f(row[col]), q2 = bf2f(row[col + 64]);
  float k1 = bf2f(row[2048 + col]), k2 = bf2f(row[2048 + col + 64]);
  long long ob = (long long)t * 2048 + col;
  qr[ob] = f2bf((q1 * c - q2 * sn) * SC);
  qr[ob + 64] = f2bf((q2 * c + q1 * sn) * SC);
  kr[ob] = f2bf(k1 * c - k2 * sn);
  kr[ob + 64] = f2bf(k2 * c + k1 * sn);
  vt[((long long)b * 2048 + col) * 2048 + s] = row[4096 + col];
  vt[((long long)b * 2048 + col + 64) * 2048 + s] = row[4096 + col + 64];
}

// ---------------- causal row softmax ----------------
__global__ __launch_bounds__(256) void softmax_causal(
    const float* __restrict__ scores, unsigned short* __restrict__ probs) {
  const int r = blockIdx.x;
  const int s = r & 2047;
  const float* src = scores + (long long)r * 2048;
  unsigned short* dst = probs + (long long)r * 2048;
  const int L = s + 1;
  __shared__ float red[4];
  float mx = -1e30f;
  for (int j = threadIdx.x; j < L; j += 256) mx = fmaxf(mx, src[j]);
#pragma unroll
  for (int m = 1; m < 64; m <<= 1) mx = fmaxf(mx, __shfl_xor(mx, m));
  if ((threadIdx.x & 63) == 0) red[threadIdx.x >> 6] = mx;
  __syncthreads();
  mx = fmaxf(fmaxf(red[0], red[1]), fmaxf(red[2], red[3]));
  float sum = 0.f;
  for (int j = threadIdx.x; j < L; j += 256) sum += __expf(src[j] - mx);
  __syncthreads();
#pragma unroll
  for (int m = 1; m < 64; m <<= 1) sum += __shfl_xor(sum, m);
  if ((threadIdx.x & 63) == 0) red[threadIdx.x >> 6] = sum;
  __syncthreads();
  const float inv = 1.f / (red[0] + red[1] + red[2] + red[3]);
  for (int j = threadIdx.x; j < 2048; j += 256)
    dst[j] = (j < L) ? f2bf(__expf(src[j] - mx) * inv) : (unsigned short)0;
}

// ---------------- old 128^2 NT GEMM (attention QK/PV only) ----------------
template <int EPI, int CAUSAL>
__global__ __launch_bounds__(256) void gemm_nt(
    const unsigned short* __restrict__ A, const unsigned short* __restrict__ Bw,
    void* __restrict__ Cp, int M, int N, int K,
    long long sAz, long long sBz, long long sCz) {
  const long long m0 = (long long)blockIdx.y * 128;
  const long long n0 = (long long)blockIdx.x * 128;
  if (CAUSAL == 1 && n0 > m0 + 127) return;
  __shared__ __align__(16) unsigned short sA[2][128 * 32];
  __shared__ __align__(16) unsigned short sB[2][128 * 32];
  const int tid = threadIdx.x;
  const int w = tid >> 6, l = tid & 63;
  const long long z = blockIdx.z;
  A += z * sAz;
  Bw += z * sBz;
  const long long cofs = z * sCz;
  const int wr = w >> 1, wc = w & 1;
  const int lrow = l & 15, lk = (l >> 4) * 8;

  f32x4 acc[4][4] = {};
  int nk = K >> 5;
  if (CAUSAL == 2) nk = (int)((m0 + 128) >> 5);
  int cur = 0;

  auto stage = [&](int buf, int k0) {
#pragma unroll
    for (int i = 0; i < 2; ++i) {
      const int flat = (w * 2 + i) * 64 + l;
      const int row = flat >> 2;
      const int col = (flat & 3) * 8;
      gload_lds16(&A[(m0 + row) * K + k0 + col], (char*)&sA[buf][0] + (w * 2 + i) * 1024);
      gload_lds16(&Bw[(n0 + row) * K + k0 + col], (char*)&sB[buf][0] + (w * 2 + i) * 1024);
    }
  };

  stage(0, 0);
  __syncthreads();
  for (int kt = 0; kt < nk; ++kt) {
    if (kt + 1 < nk) stage(cur ^ 1, (kt + 1) << 5);
    short8 af[4], bfr[4];
#pragma unroll
    for (int m = 0; m < 4; ++m)
      af[m] = *(const short8*)&sA[cur][(wr * 64 + m * 16 + lrow) * 32 + lk];
#pragma unroll
    for (int n = 0; n < 4; ++n)
      bfr[n] = *(const short8*)&sB[cur][(wc * 64 + n * 16 + lrow) * 32 + lk];
#pragma unroll
    for (int m = 0; m < 4; ++m)
#pragma unroll
      for (int n = 0; n < 4; ++n)
        acc[m][n] = mfma16(af[m], bfr[n], acc[m][n]);
    __syncthreads();
    cur ^= 1;
  }

  const int orow = (l >> 4) * 4, ocol = l & 15;
#pragma unroll
  for (int m = 0; m < 4; ++m)
#pragma unroll
    for (int n = 0; n < 4; ++n)
#pragma unroll
      for (int r = 0; r < 4; ++r) {
        long long gr = m0 + wr * 64 + m * 16 + orow + r;
        long long gc = n0 + wc * 64 + n * 16 + ocol;
        long long idx = cofs + gr * N + gc;
        float v = acc[m][n][r];
        if (EPI == 0) ((unsigned short*)Cp)[idx] = f2bf(v);
        else ((float*)Cp)[idx] = v;
      }
}

// ---------------- 256^2 NT GEMM: BK=64 dbuf, 32x32x16 MFMA ----------------
// 8 waves (2Mx4N), wave tile 128x64 of 32x32 frags (4m x 2n).
// LDS rows 128B, XOR window swizzle w ^= row&7 (pre-swizzled global source,
// linear LDS dest, swizzled ds_read). Stage(g+2) after trailing barrier
// (all lgkm drains done -> no overwrite race), vmcnt(8) counted.
template <int EPI>
__global__ __launch_bounds__(512, 2) void gemm256(
    const unsigned short* __restrict__ A, const unsigned short* __restrict__ Bw,
    void* __restrict__ Cp, const void* __restrict__ Ep,
    int N, int K, int nbx, int kLen, int ng, long long zCout) {
  __shared__ __align__(16) unsigned short lds[2 * 2 * 16384];  // 128KB
  __shared__ __align__(16) unsigned short ldsDummy[512];       // 1KB sink
  const int tid = threadIdx.x;
  const int wid = tid >> 6, l = tid & 63;
  const int wr = wid >> 2, wcn = wid & 3;

  // 2D-brick XCD schedule (4x8 block bricks per 32 consecutive lin ids)
  const int nwg = gridDim.x;  // divisible by 32; nbx divisible by 8
  const int q8 = nwg >> 3;
  const int lin = (blockIdx.x & 7) * q8 + (blockIdx.x >> 3);
  const int t32 = lin >> 5, r32 = lin & 31;
  const int tpr = nbx >> 3;
  const int tm = t32 / tpr, tn = t32 - tm * tpr;
  const long long m0 = (long long)(tm * 4 + (r32 >> 3)) * 256;
  const long long n0 = (long long)(tn * 8 + (r32 & 7)) * 256;
  const int z = blockIdx.z;
  const long long kbase = (long long)z * kLen;
  const long long zofs = (long long)z * zCout;

  // staging: lane l covers row (l>>3) of its 8-row block, source col window
  // pre-swizzled by row&7 so LDS[r][w] = global[r][w ^ (r&7)]
  const int sRow = l >> 3;
  const int sCol = ((l & 7) ^ (l >> 3)) * 8;
  auto stage = [&](int g) {
    if (g < ng) {
      const long long kcol = kbase + (long long)g * 64 + sCol;
      char* base = (char*)lds + (g & 1) * 65536;
#pragma unroll
      for (int mat = 0; mat < 2; ++mat) {
        const unsigned short* src = mat ? Bw : A;
        const long long rb = mat ? n0 : m0;
#pragma unroll
        for (int li = 0; li < 4; ++li) {
          const int r = wid * 32 + li * 8 + sRow;
          gload_lds16(&src[(rb + r) * K + kcol],
                      base + mat * 32768 + (wid * 4 + li) * 1024);
        }
      }
    } else {
#pragma unroll
      for (int i = 0; i < 8; ++i) gload_lds16(&A[m0 * K], (char*)ldsDummy);
    }
  };

  const int rl31 = l & 31, rl7 = l & 7, rhi = l >> 5;

  f32x16 acc[4][2] = {};

  stage(0);
  stage(1);
  asm volatile("s_waitcnt vmcnt(8)" ::: "memory");
  __builtin_amdgcn_s_barrier();

  for (int g = 0; g < ng; ++g) {
    const char* sA = (const char*)lds + (g & 1) * 65536;
    const char* sB = sA + 32768;
    short8 af[2][4], bf[2][4];
    // ---- phase 0: A m{0,1}, B n{0,1} ----
#pragma unroll
    for (int m = 0; m < 2; ++m)
#pragma unroll
      for (int s = 0; s < 4; ++s) {
        const int row = wr * 128 + m * 32 + rl31;
        const int w = (s * 2 + rhi) ^ rl7;
        af[m][s] = *(const short8*)(sA + row * 128 + w * 16);
      }
#pragma unroll
    for (int n = 0; n < 2; ++n)
#pragma unroll
      for (int s = 0; s < 4; ++s) {
        const int row = wcn * 64 + n * 32 + rl31;
        const int w = (s * 2 + rhi) ^ rl7;
        bf[n][s] = *(const short8*)(sB + row * 128 + w * 16);
      }
    __builtin_amdgcn_s_barrier();
    asm volatile("s_waitcnt lgkmcnt(0)" ::: "memory");
    __builtin_amdgcn_sched_barrier(0);
    __builtin_amdgcn_s_setprio(1);
#pragma unroll
    for (int m = 0; m < 2; ++m)
#pragma unroll
      for (int n = 0; n < 2; ++n)
#pragma unroll
        for (int s = 0; s < 4; ++s)
          acc[m][n] = mfma32(af[m][s], bf[n][s], acc[m][n]);
    __builtin_amdgcn_s_setprio(0);
    __builtin_amdgcn_s_barrier();
    // ---- phase 1: A m{2,3} (B frags resident) ----
#pragma unroll
    for (int m = 0; m < 2; ++m)
#pragma unroll
      for (int s = 0; s < 4; ++s) {
        const int row = wr * 128 + (m + 2) * 32 + rl31;
        const int w = (s * 2 + rhi) ^ rl7;
        af[m][s] = *(const short8*)(sA + row * 128 + w * 16);
      }
    __builtin_amdgcn_s_barrier();
    asm volatile("s_waitcnt lgkmcnt(0)" ::: "memory");
    __builtin_amdgcn_sched_barrier(0);
    __builtin_amdgcn_s_setprio(1);
#pragma unroll
    for (int m = 0; m < 2; ++m)
#pragma unroll
      for (int n = 0; n < 2; ++n)
#pragma unroll
        for (int s = 0; s < 4; ++s)
          acc[m + 2][n] = mfma32(af[m][s], bf[n][s], acc[m + 2][n]);
    __builtin_amdgcn_s_setprio(0);
    __builtin_amdgcn_s_barrier();
    // ---- rotate: stage g+2 into the buffer just consumed ----
    stage(g + 2);
    asm volatile("s_waitcnt vmcnt(8)" ::: "memory");  // g+1 fully landed
    __builtin_amdgcn_s_barrier();
  }

  const long long cm = m0 + wr * 128;
  const long long cn = n0 + wcn * 64;
#pragma unroll
  for (int m = 0; m < 4; ++m)
#pragma unroll
    for (int n = 0; n < 2; ++n)
#pragma unroll
      for (int r = 0; r < 16; ++r) {
        const long long gr = cm + m * 32 + (r & 3) + 8 * (r >> 2) + 4 * rhi;
        const long long gc = cn + n * 32 + rl31;
        const long long idx = zofs + gr * N + gc;
        const float v = acc[m][n][r];
        if (EPI == 0) {
          ((unsigned short*)Cp)[idx] = f2bf(v);
        } else if (EPI == 2) {
          ((unsigned short*)Cp)[idx] = f2bf(bf2f(((const unsigned short*)Ep)[idx]) * v);
        } else {
          ((float*)Cp)[idx] = v;
        }
      }
}

// ---------------- split-K combine ----------------
__global__ __launch_bounds__(256) void combine2(
    const float* __restrict__ ep, const float* __restrict__ p,
    float* __restrict__ out, long long n4) {
  const float4* e4 = (const float4*)ep;
  const float4* p4 = (const float4*)p;
  float4* o4 = (float4*)out;
  for (long long i = blockIdx.x * 256 + threadIdx.x; i < n4; i += 2048 * 256) {
    float4 a = e4[i], b = p4[i], c = p4[i + n4];
    float4 o;
    o.x = a.x + b.x + c.x; o.y = a.y + b.y + c.y;
    o.z = a.z + b.z + c.z; o.w = a.w + b.w + c.w;
    o4[i] = o;
  }
}

extern "C" void kernel_launch(void* const* d_in, const int* in_sizes, int n_in,
                              void* d_out, int out_size, void* d_ws, size_t ws_size,
                              hipStream_t stream) {
  (void)in_sizes; (void)n_in; (void)out_size; (void)ws_size;
  const float* hidden = (const float*)d_in[0];
  const float* cosT = (const float*)d_in[2];
  const float* sinT = (const float*)d_in[3];
  const float* wq = (const float*)d_in[4];
  const float* wk = (const float*)d_in[5];
  const float* wv = (const float*)d_in[6];
  const float* wo = (const float*)d_in[7];
  const float* wg = (const float*)d_in[8];
  const float* wu = (const float*)d_in[9];
  const float* wd = (const float*)d_in[10];
  const float* ln1 = (const float*)d_in[11];
  const float* ln2 = (const float*)d_in[12];

  const size_t MB = 1ull << 20;
  char* ws = (char*)d_ws;
  unsigned short* xn    = (unsigned short*)(ws + 0);        // 16MB
  unsigned short* wqkvq = (unsigned short*)(ws + 16 * MB);  // 24MB
  unsigned short* qkv   = (unsigned short*)(ws + 40 * MB);  // 48MB
  unsigned short* qrb   = (unsigned short*)(ws + 88 * MB);  // 16MB
  unsigned short* krb   = (unsigned short*)(ws + 104 * MB); // 16MB
  unsigned short* vtb   = (unsigned short*)(ws + 120 * MB); // 16MB
  float*          scoresB = (float*)(ws + 0);               // 32MB alias
  unsigned short* probsB  = (unsigned short*)(ws + 40 * MB);// 16MB alias
  float*          part   = (float*)(ws + 0);                // 64MB alias
  unsigned short* wgq   = (unsigned short*)(ws + 0);        // 32MB alias
  unsigned short* wuq   = (unsigned short*)(ws + 32 * MB);  // 32MB alias
  unsigned short* gbuf  = (unsigned short*)(ws + 64 * MB);  // 64MB alias
  unsigned short* attnb = (unsigned short*)(ws + 136 * MB); // 16MB
  unsigned short* woq   = (unsigned short*)(ws + 152 * MB); // 8MB
  float*          hbuf  = (float*)(ws + 160 * MB);          // 32MB
  unsigned short* ybuf  = (unsigned short*)(ws + 192 * MB); // 16MB
  unsigned short* gated = (unsigned short*)(ws + 208 * MB); // 64MB
  unsigned short* wdq   = (unsigned short*)(ws + 272 * MB); // 32MB
  float* wspart         = (float*)(ws + 304 * MB);          // 28KB
  float* scales         = (float*)(ws + 304 * MB + 32768);

  // --- scales ---
  MArgs am;
  am.src[0] = wq; am.src[1] = wk; am.src[2] = wv; am.src[3] = wo;
  am.src[4] = wg; am.src[5] = wu; am.src[6] = wd;
  am.n[0] = am.n[1] = am.n[2] = am.n[3] = 4194304;
  am.n[4] = am.n[5] = am.n[6] = 16777216;
  for (int i = 0; i < 7; ++i) { am.dst[i] = nullptr; am.sidx[i] = i; }
  absmean_partial_multi<<<dim3(1024, 7), 256, 0, stream>>>(am, wspart);
  absmean_final<<<7, 256, 0, stream>>>(wspart, scales);

  // --- early quantize: wq,wk,wv,wo,wd ---
  MArgs qe;
  qe.src[0] = wq; qe.dst[0] = wqkvq;            qe.n[0] = 4194304;  qe.sidx[0] = 0;
  qe.src[1] = wk; qe.dst[1] = wqkvq + 4194304;  qe.n[1] = 4194304;  qe.sidx[1] = 1;
  qe.src[2] = wv; qe.dst[2] = wqkvq + 8388608;  qe.n[2] = 4194304;  qe.sidx[2] = 2;
  qe.src[3] = wo; qe.dst[3] = woq;              qe.n[3] = 4194304;  qe.sidx[3] = 3;
  qe.src[4] = wd; qe.dst[4] = wdq;              qe.n[4] = 16777216; qe.sidx[4] = 6;
  qe.src[5] = wq; qe.dst[5] = nullptr; qe.n[5] = 0; qe.sidx[5] = 0;
  qe.src[6] = wq; qe.dst[6] = nullptr; qe.n[6] = 0; qe.sidx[6] = 0;
  quantize_multi<<<dim3(2048, 5), 256, 0, stream>>>(qe, scales);

  rmsnorm_k<<<4096, 256, 0, stream>>>(hidden, ln1, xn);

  // QKV: [4096x6144x2048], grid 384, ng = 2048/64 = 32
  gemm256<0><<<dim3(384, 1, 1), 512, 0, stream>>>(
      xn, wqkvq, qkv, nullptr, 6144, 2048, 24, 2048, 32, 0);

  rope_k<<<16384, 256, 0, stream>>>(qkv, cosT, sinT, qrb, krb, vtb);

  // attention (full-D per batch, causal)
  gemm_nt<4, 1><<<dim3(16, 16, 2), 256, 0, stream>>>(
      qrb, krb, scoresB, 2048, 2048, 2048, 4194304, 4194304, 4194304);
  softmax_causal<<<4096, 256, 0, stream>>>(scoresB, probsB);
  gemm_nt<0, 2><<<dim3(16, 16, 2), 256, 0, stream>>>(
      probsB, vtb, attnb, 2048, 2048, 2048, 4194304, 4194304, 4194304);

  // O-proj: split-K=2 -> combine with residual
  gemm256<4><<<dim3(128, 1, 2), 512, 0, stream>>>(
      attnb, woq, part, nullptr, 2048, 2048, 8, 1024, 16, 8388608);
  combine2<<<2048, 256, 0, stream>>>(hidden, part, hbuf, 2097152);

  // late quantize: wg, wu
  MArgs ql;
  ql.src[0] = wg; ql.dst[0] = wgq; ql.n[0] = 16777216; ql.sidx[0] = 4;
  ql.src[1] = wu; ql.dst[1] = wuq; ql.n[1] = 16777216; ql.sidx[1] = 5;
  for (int i = 2; i < 7; ++i) { ql.src[i] = wg; ql.dst[i] = nullptr; ql.n[i] = 0; ql.sidx[i] = 0; }
  quantize_multi<<<dim3(2048, 2), 256, 0, stream>>>(ql, scales);

  rmsnorm_k<<<4096, 256, 0, stream>>>(hbuf, ln2, ybuf);

  // G, U: [4096x8192x2048], grid 512, ng 32
  gemm256<0><<<dim3(512, 1, 1), 512, 0, stream>>>(
      ybuf, wgq, gbuf, nullptr, 8192, 2048, 32, 2048, 32, 0);
  gemm256<2><<<dim3(512, 1, 1), 512, 0, stream>>>(
      ybuf, wuq, gated, gbuf, 8192, 2048, 32, 2048, 32, 0);

  // D: [4096x2048x8192] split-K=2 -> combine into d_out
  gemm256<4><<<dim3(128, 1, 2), 512, 0, stream>>>(
      gated, wdq, part, nullptr, 2048, 8192, 8, 4096, 64, 8388608);
  combine2<<<2048, 256, 0, stream>>>(hbuf, part, (float*)d_out, 2097152);
}

// Round 6
// 949.327 us; speedup vs baseline: 1.0349x; 1.0349x over previous
//
#include <hip/hip_runtime.h>
#include <stdint.h>

#define DEV __device__ __forceinline__

typedef __attribute__((ext_vector_type(8))) short short8;
typedef __attribute__((ext_vector_type(8))) __bf16 bf16x8;
typedef __attribute__((ext_vector_type(16))) float f32x16;

DEV unsigned short f2bf(float f) {
  union { float f; unsigned int u; } v; v.f = f;
  unsigned int r = v.u + 0x7fffu + ((v.u >> 16) & 1u);
  return (unsigned short)(r >> 16);
}
DEV float bf2f(unsigned short h) {
  union { unsigned int u; float f; } v; v.u = ((unsigned int)h) << 16;
  return v.f;
}
DEV f32x16 mfma32(short8 a, short8 b, f32x16 c) {
  return __builtin_amdgcn_mfma_f32_32x32x16_bf16(
      __builtin_bit_cast(bf16x8, a), __builtin_bit_cast(bf16x8, b), c, 0, 0, 0);
}
DEV void gload_lds16(const void* g, void* lds) {
  __builtin_amdgcn_global_load_lds(
      (const __attribute__((address_space(1))) void*)g,
      (__attribute__((address_space(3))) void*)lds, 16, 0, 0);
}

struct MArgs {
  const float* src[7];
  unsigned short* dst[7];
  int n[7];
  int sidx[7];
};

// ---------------- abs-mean partial (all matrices, one launch) ----------------
__global__ __launch_bounds__(256) void absmean_partial_multi(
    MArgs a, float* __restrict__ partial) {
  const int m = blockIdx.y;
  const float4* w4 = (const float4*)a.src[m];
  const int n4 = a.n[m] >> 2;
  float s = 0.f;
  for (int i = blockIdx.x * 256 + threadIdx.x; i < n4; i += 1024 * 256) {
    float4 v = w4[i];
    s += fabsf(v.x) + fabsf(v.y) + fabsf(v.z) + fabsf(v.w);
  }
#pragma unroll
  for (int mm = 1; mm < 64; mm <<= 1) s += __shfl_xor(s, mm);
  __shared__ float red[4];
  if ((threadIdx.x & 63) == 0) red[threadIdx.x >> 6] = s;
  __syncthreads();
  if (threadIdx.x == 0)
    partial[m * 1024 + blockIdx.x] = red[0] + red[1] + red[2] + red[3];
}

__global__ __launch_bounds__(256) void absmean_final(
    const float* __restrict__ partial, float* __restrict__ scales) {
  __shared__ double red[256];
  const int m = blockIdx.x;
  double s = 0.0;
  for (int i = threadIdx.x; i < 1024; i += 256) s += (double)partial[m * 1024 + i];
  red[threadIdx.x] = s;
  __syncthreads();
  for (int t = 128; t > 0; t >>= 1) {
    if (threadIdx.x < t) red[threadIdx.x] += red[threadIdx.x + t];
    __syncthreads();
  }
  if (threadIdx.x == 0) {
    const long long cnt = (m < 4) ? 4194304ll : 16777216ll;
    scales[m] = (float)(red[0] / (double)cnt);
  }
}

// ---------------- ternary quantize -> bf16 (batched) ----------------
__global__ __launch_bounds__(256) void quantize_multi(
    MArgs a, const float* __restrict__ scales) {
  const int m = blockIdx.y;
  const float sc = scales[a.sidx[m]];
  const float inv = 1.f / (sc + 1e-5f);
  const float4* src = (const float4*)a.src[m];
  ushort4* dst = (ushort4*)a.dst[m];
  const int n4 = a.n[m] >> 2;
  for (int i = blockIdx.x * 256 + threadIdx.x; i < n4; i += 2048 * 256) {
    float4 v = src[i];
    ushort4 o;
    o.x = f2bf(fminf(fmaxf(rintf(v.x * inv), -1.f), 1.f) * sc);
    o.y = f2bf(fminf(fmaxf(rintf(v.y * inv), -1.f), 1.f) * sc);
    o.z = f2bf(fminf(fmaxf(rintf(v.z * inv), -1.f), 1.f) * sc);
    o.w = f2bf(fminf(fmaxf(rintf(v.w * inv), -1.f), 1.f) * sc);
    dst[i] = o;
  }
}

// ---------------- RMSNorm (f32 in -> bf16 out) ----------------
__global__ __launch_bounds__(256) void rmsnorm_k(
    const float* __restrict__ x, const float* __restrict__ wt,
    unsigned short* __restrict__ out) {
  const long long t = blockIdx.x;
  const float* xr = x + t * 2048;
  const int i0 = threadIdx.x * 8;
  float4 a = *(const float4*)(xr + i0);
  float4 b = *(const float4*)(xr + i0 + 4);
  float ss = a.x * a.x + a.y * a.y + a.z * a.z + a.w * a.w +
             b.x * b.x + b.y * b.y + b.z * b.z + b.w * b.w;
#pragma unroll
  for (int m = 1; m < 64; m <<= 1) ss += __shfl_xor(ss, m);
  __shared__ float red[4];
  if ((threadIdx.x & 63) == 0) red[threadIdx.x >> 6] = ss;
  __syncthreads();
  float tot = red[0] + red[1] + red[2] + red[3];
  float rs = rsqrtf(tot * (1.f / 2048.f) + 1e-5f);
  float4 wa = *(const float4*)(wt + i0);
  float4 wb = *(const float4*)(wt + i0 + 4);
  ushort4 o1, o2;
  o1.x = f2bf(a.x * wa.x * rs); o1.y = f2bf(a.y * wa.y * rs);
  o1.z = f2bf(a.z * wa.z * rs); o1.w = f2bf(a.w * wa.w * rs);
  o2.x = f2bf(b.x * wb.x * rs); o2.y = f2bf(b.y * wb.y * rs);
  o2.z = f2bf(b.z * wb.z * rs); o2.w = f2bf(b.w * wb.w * rs);
  *(ushort4*)(out + t * 2048 + i0) = o1;
  *(ushort4*)(out + t * 2048 + i0 + 4) = o2;
}

// ---------------- RoPE + V transpose ----------------
__global__ __launch_bounds__(256) void rope_k(
    const unsigned short* __restrict__ qkv, const float* __restrict__ cosT,
    const float* __restrict__ sinT, unsigned short* __restrict__ qr,
    unsigned short* __restrict__ kr, unsigned short* __restrict__ vt) {
  const long long gid = (long long)blockIdx.x * 256 + threadIdx.x;
  const int t = (int)(gid >> 10);
  const int r = (int)(gid & 1023);
  const int h = r >> 6, d = r & 63;
  const int s = t & 2047, b = t >> 11;
  const unsigned short* row = qkv + (long long)t * 6144;
  const float c = cosT[s * 128 + d], sn = sinT[s * 128 + d];
  const int col = h * 128 + d;
  const float SC = 0.08838834764831845f;  // 1/sqrt(128)
  float q1 = bf2f(row[col]), q2 = bf2f(row[col + 64]);
  float k1 = bf2f(row[2048 + col]), k2 = bf2f(row[2048 + col + 64]);
  long long ob = (long long)t * 2048 + col;
  qr[ob] = f2bf((q1 * c - q2 * sn) * SC);
  qr[ob + 64] = f2bf((q2 * c + q1 * sn) * SC);
  kr[ob] = f2bf(k1 * c - k2 * sn);
  kr[ob + 64] = f2bf(k2 * c + k1 * sn);
  vt[((long long)b * 2048 + col) * 2048 + s] = row[4096 + col];
  vt[((long long)b * 2048 + col + 64) * 2048 + s] = row[4096 + col + 64];
}

// ---------------- causal row softmax (single global read, regs) ----------------
__global__ __launch_bounds__(256) void softmax_causal(
    const float* __restrict__ scores, unsigned short* __restrict__ probs) {
  const int r = blockIdx.x;
  const int s = r & 2047;
  const float* src = scores + (long long)r * 2048;
  unsigned short* dst = probs + (long long)r * 2048;
  const int L = s + 1;
  const int j0 = threadIdx.x * 8;
  float4 a = *(const float4*)(src + j0);
  float4 b = *(const float4*)(src + j0 + 4);
  float v[8] = {a.x, a.y, a.z, a.w, b.x, b.y, b.z, b.w};
  float mx = -1e30f;
#pragma unroll
  for (int i = 0; i < 8; ++i) {
    if (j0 + i >= L) v[i] = -1e30f;
    mx = fmaxf(mx, v[i]);
  }
#pragma unroll
  for (int m = 1; m < 64; m <<= 1) mx = fmaxf(mx, __shfl_xor(mx, m));
  __shared__ float redM[4], redS[4];
  if ((threadIdx.x & 63) == 0) redM[threadIdx.x >> 6] = mx;
  __syncthreads();
  mx = fmaxf(fmaxf(redM[0], redM[1]), fmaxf(redM[2], redM[3]));
  float sum = 0.f;
#pragma unroll
  for (int i = 0; i < 8; ++i) {
    v[i] = (j0 + i < L) ? __expf(v[i] - mx) : 0.f;
    sum += v[i];
  }
#pragma unroll
  for (int m = 1; m < 64; m <<= 1) sum += __shfl_xor(sum, m);
  if ((threadIdx.x & 63) == 0) redS[threadIdx.x >> 6] = sum;
  __syncthreads();
  const float inv = 1.f / (redS[0] + redS[1] + redS[2] + redS[3]);
  ushort4 o1, o2;
  o1.x = f2bf(v[0] * inv); o1.y = f2bf(v[1] * inv);
  o1.z = f2bf(v[2] * inv); o1.w = f2bf(v[3] * inv);
  o2.x = f2bf(v[4] * inv); o2.y = f2bf(v[5] * inv);
  o2.z = f2bf(v[6] * inv); o2.w = f2bf(v[7] * inv);
  *(ushort4*)(dst + j0) = o1;
  *(ushort4*)(dst + j0 + 4) = o2;
}

// ---------------- 256^2 NT GEMM: round-4 structure + 32x32x16 MFMA ----------------
// 8 waves (2Mx4N), wave tile 128x64 as 4m x 2n frags of 32x32.
// BK=32, 4-slot K-chunk ring, round-4 staging/swizzle (PMC-verified 0-conflict):
// LDS[r][w] = global[r][w ^ ((r>>1)&3)], rows 64B, windows 16B.
// EPI 0: bf16. 2: bf16 = Ep(bf16)*acc. 4: f32 raw at +z*zCout.
// CAUSAL 0: none. 1: skip 256-blocks with n0 > m0. 2: K-limit ng to (m0+256)/32.
template <int EPI, int CAUSAL>
__global__ __launch_bounds__(512, 2) void gemm256(
    const unsigned short* __restrict__ A, const unsigned short* __restrict__ Bw,
    void* __restrict__ Cp, const void* __restrict__ Ep,
    int N, int K, int nbx, int kLen, int ngTot,
    long long sAz, long long sBz, long long zCout) {
  __shared__ __align__(16) unsigned short lds[4 * 2 * 8192];  // 128KB
  __shared__ __align__(16) unsigned short ldsDummy[512];      // 1KB sink
  const int tid = threadIdx.x;
  const int wid = tid >> 6, l = tid & 63;
  const int wr = wid >> 2, wcn = wid & 3;

  // 2D-brick XCD schedule (4x8 block bricks per 32 consecutive lin ids)
  const int nwg = gridDim.x;  // divisible by 32; nbx divisible by 8
  const int q8 = nwg >> 3;
  const int lin = (blockIdx.x & 7) * q8 + (blockIdx.x >> 3);
  const int t32 = lin >> 5, r32 = lin & 31;
  const int tpr = nbx >> 3;
  const int tm = t32 / tpr, tn = t32 - tm * tpr;
  const long long m0 = (long long)(tm * 4 + (r32 >> 3)) * 256;
  const long long n0 = (long long)(tn * 8 + (r32 & 7)) * 256;
  if (CAUSAL == 1 && n0 > m0) return;
  const int z = blockIdx.z;
  A += z * sAz;
  Bw += z * sBz;
  const long long kbase = (long long)z * kLen;
  const long long zofs = (long long)z * zCout;
  int ng = ngTot;
  if (CAUSAL == 2) {
    const int lim = (int)((m0 + 256) >> 5);
    ng = lim < ng ? lim : ng;
  }

  // round-4 staging (byte-identical LDS content)
  const int stRow = (l >> 2);
  const int stCol = (((l & 3) ^ ((l >> 3) & 3))) * 8;  // pre-swizzled source col
  auto stage = [&](int chunk, int mat) {
    char* base = (char*)lds + (((chunk & 3) * 2 + mat) * 16384);
    const unsigned short* src = mat ? Bw : A;
    const long long rb = mat ? n0 : m0;
    if (chunk < ng) {
      const long long kcol = kbase + (long long)chunk * 32 + stCol;
#pragma unroll
      for (int i = 0; i < 2; ++i) {
        const int row = (wid * 2 + i) * 16 + stRow;
        gload_lds16(&src[(rb + row) * K + kcol], base + (wid * 2 + i) * 1024);
      }
    } else {
#pragma unroll
      for (int i = 0; i < 2; ++i) gload_lds16(&src[rb * K], (char*)ldsDummy);
    }
  };

  // 32x32 frag read: row = base + (l&31); k-window w0 = s*2 + (l>>5);
  // swizzled window w = w0 ^ ((row>>1)&3) = w0 ^ ((rl31>>1)&3)
  const int rl31 = l & 31, rhi = l >> 5;
  const int rsw = (rl31 >> 1) & 3;

  f32x16 acc[4][2] = {};

  stage(0, 0); stage(0, 1);
  stage(1, 0); stage(1, 1);
  stage(2, 0); stage(2, 1);
  asm volatile("s_waitcnt vmcnt(8)" ::: "memory");
  __builtin_amdgcn_s_barrier();

  for (int c = 0; c < ng; ++c) {
    const int slot = c & 3;
    const char* sA = (const char*)lds + (slot * 2 + 0) * 16384;
    const char* sB = (const char*)lds + (slot * 2 + 1) * 16384;
    short8 af[2][2], bfr[2][2];
    // ---- phase 0: A m{0,1}, B n{0,1} ----
#pragma unroll
    for (int m = 0; m < 2; ++m)
#pragma unroll
      for (int s = 0; s < 2; ++s)
        af[m][s] = *(const short8*)(sA + (wr * 128 + m * 32 + rl31) * 64 +
                                    (((s * 2 + rhi) ^ rsw) << 4));
#pragma unroll
    for (int n = 0; n < 2; ++n)
#pragma unroll
      for (int s = 0; s < 2; ++s)
        bfr[n][s] = *(const short8*)(sB + (wcn * 64 + n * 32 + rl31) * 64 +
                                     (((s * 2 + rhi) ^ rsw) << 4));
    stage(c + 3, 0);
    __builtin_amdgcn_s_barrier();
    asm volatile("s_waitcnt lgkmcnt(0)" ::: "memory");
    __builtin_amdgcn_sched_barrier(0);
    __builtin_amdgcn_s_setprio(1);
#pragma unroll
    for (int m = 0; m < 2; ++m)
#pragma unroll
      for (int n = 0; n < 2; ++n)
#pragma unroll
        for (int s = 0; s < 2; ++s)
          acc[m][n] = mfma32(af[m][s], bfr[n][s], acc[m][n]);
    __builtin_amdgcn_s_setprio(0);
    __builtin_amdgcn_s_barrier();
    // ---- phase 1: A m{2,3} (B frags resident) ----
#pragma unroll
    for (int m = 0; m < 2; ++m)
#pragma unroll
      for (int s = 0; s < 2; ++s)
        af[m][s] = *(const short8*)(sA + (wr * 128 + (m + 2) * 32 + rl31) * 64 +
                                    (((s * 2 + rhi) ^ rsw) << 4));
    stage(c + 3, 1);
    __builtin_amdgcn_s_barrier();
    asm volatile("s_waitcnt lgkmcnt(0)" ::: "memory");
    __builtin_amdgcn_sched_barrier(0);
    __builtin_amdgcn_s_setprio(1);
#pragma unroll
    for (int m = 0; m < 2; ++m)
#pragma unroll
      for (int n = 0; n < 2; ++n)
#pragma unroll
        for (int s = 0; s < 2; ++s)
          acc[m + 2][n] = mfma32(af[m][s], bfr[n][s], acc[m + 2][n]);
    __builtin_amdgcn_s_setprio(0);
    asm volatile("s_waitcnt vmcnt(8)" ::: "memory");
    __builtin_amdgcn_s_barrier();
  }
  asm volatile("s_waitcnt vmcnt(0)" ::: "memory");
  __builtin_amdgcn_s_barrier();

  // C/D 32x32 mapping (verified round 5): row = (r&3) + 8*(r>>2) + 4*rhi, col = rl31
  const long long cm = m0 + wr * 128;
  const long long cn = n0 + wcn * 64;
#pragma unroll
  for (int m = 0; m < 4; ++m)
#pragma unroll
    for (int n = 0; n < 2; ++n)
#pragma unroll
      for (int r = 0; r < 16; ++r) {
        const long long gr = cm + m * 32 + (r & 3) + 8 * (r >> 2) + 4 * rhi;
        const long long gc = cn + n * 32 + rl31;
        const long long idx = zofs + gr * N + gc;
        const float v = acc[m][n][r];
        if (EPI == 0) {
          ((unsigned short*)Cp)[idx] = f2bf(v);
        } else if (EPI == 2) {
          ((unsigned short*)Cp)[idx] = f2bf(bf2f(((const unsigned short*)Ep)[idx]) * v);
        } else {
          ((float*)Cp)[idx] = v;
        }
      }
}

// ---------------- split-K combine ----------------
__global__ __launch_bounds__(256) void combine2(
    const float* __restrict__ ep, const float* __restrict__ p,
    float* __restrict__ out, long long n4) {
  const float4* e4 = (const float4*)ep;
  const float4* p4 = (const float4*)p;
  float4* o4 = (float4*)out;
  for (long long i = blockIdx.x * 256 + threadIdx.x; i < n4; i += 2048 * 256) {
    float4 a = e4[i], b = p4[i], c = p4[i + n4];
    float4 o;
    o.x = a.x + b.x + c.x; o.y = a.y + b.y + c.y;
    o.z = a.z + b.z + c.z; o.w = a.w + b.w + c.w;
    o4[i] = o;
  }
}

extern "C" void kernel_launch(void* const* d_in, const int* in_sizes, int n_in,
                              void* d_out, int out_size, void* d_ws, size_t ws_size,
                              hipStream_t stream) {
  (void)in_sizes; (void)n_in; (void)out_size; (void)ws_size;
  const float* hidden = (const float*)d_in[0];
  const float* cosT = (const float*)d_in[2];
  const float* sinT = (const float*)d_in[3];
  const float* wq = (const float*)d_in[4];
  const float* wk = (const float*)d_in[5];
  const float* wv = (const float*)d_in[6];
  const float* wo = (const float*)d_in[7];
  const float* wg = (const float*)d_in[8];
  const float* wu = (const float*)d_in[9];
  const float* wd = (const float*)d_in[10];
  const float* ln1 = (const float*)d_in[11];
  const float* ln2 = (const float*)d_in[12];

  const size_t MB = 1ull << 20;
  char* ws = (char*)d_ws;
  unsigned short* xn    = (unsigned short*)(ws + 0);        // 16MB
  unsigned short* wqkvq = (unsigned short*)(ws + 16 * MB);  // 24MB
  unsigned short* qkv   = (unsigned short*)(ws + 40 * MB);  // 48MB
  unsigned short* qrb   = (unsigned short*)(ws + 88 * MB);  // 16MB
  unsigned short* krb   = (unsigned short*)(ws + 104 * MB); // 16MB
  unsigned short* vtb   = (unsigned short*)(ws + 120 * MB); // 16MB
  float*          scoresB = (float*)(ws + 0);               // 32MB alias
  unsigned short* probsB  = (unsigned short*)(ws + 40 * MB);// 16MB alias
  float*          part   = (float*)(ws + 0);                // 64MB alias
  unsigned short* wgq   = (unsigned short*)(ws + 0);        // 32MB alias
  unsigned short* wuq   = (unsigned short*)(ws + 32 * MB);  // 32MB alias
  unsigned short* gbuf  = (unsigned short*)(ws + 64 * MB);  // 64MB alias
  unsigned short* attnb = (unsigned short*)(ws + 136 * MB); // 16MB
  unsigned short* woq   = (unsigned short*)(ws + 152 * MB); // 8MB
  float*          hbuf  = (float*)(ws + 160 * MB);          // 32MB
  unsigned short* ybuf  = (unsigned short*)(ws + 192 * MB); // 16MB
  unsigned short* gated = (unsigned short*)(ws + 208 * MB); // 64MB
  unsigned short* wdq   = (unsigned short*)(ws + 272 * MB); // 32MB
  float* wspart         = (float*)(ws + 304 * MB);          // 28KB
  float* scales         = (float*)(ws + 304 * MB + 32768);

  // --- scales ---
  MArgs am;
  am.src[0] = wq; am.src[1] = wk; am.src[2] = wv; am.src[3] = wo;
  am.src[4] = wg; am.src[5] = wu; am.src[6] = wd;
  am.n[0] = am.n[1] = am.n[2] = am.n[3] = 4194304;
  am.n[4] = am.n[5] = am.n[6] = 16777216;
  for (int i = 0; i < 7; ++i) { am.dst[i] = nullptr; am.sidx[i] = i; }
  absmean_partial_multi<<<dim3(1024, 7), 256, 0, stream>>>(am, wspart);
  absmean_final<<<7, 256, 0, stream>>>(wspart, scales);

  // --- early quantize: wq,wk,wv,wo,wd ---
  MArgs qe;
  qe.src[0] = wq; qe.dst[0] = wqkvq;            qe.n[0] = 4194304;  qe.sidx[0] = 0;
  qe.src[1] = wk; qe.dst[1] = wqkvq + 4194304;  qe.n[1] = 4194304;  qe.sidx[1] = 1;
  qe.src[2] = wv; qe.dst[2] = wqkvq + 8388608;  qe.n[2] = 4194304;  qe.sidx[2] = 2;
  qe.src[3] = wo; qe.dst[3] = woq;              qe.n[3] = 4194304;  qe.sidx[3] = 3;
  qe.src[4] = wd; qe.dst[4] = wdq;              qe.n[4] = 16777216; qe.sidx[4] = 6;
  qe.src[5] = wq; qe.dst[5] = nullptr; qe.n[5] = 0; qe.sidx[5] = 0;
  qe.src[6] = wq; qe.dst[6] = nullptr; qe.n[6] = 0; qe.sidx[6] = 0;
  quantize_multi<<<dim3(2048, 5), 256, 0, stream>>>(qe, scales);

  rmsnorm_k<<<4096, 256, 0, stream>>>(hidden, ln1, xn);

  // QKV: [4096x6144x2048], grid 384, 64 K-chunks
  gemm256<0, 0><<<dim3(384, 1, 1), 512, 0, stream>>>(
      xn, wqkvq, qkv, nullptr, 6144, 2048, 24, 2048, 64, 0, 0, 0);

  rope_k<<<16384, 256, 0, stream>>>(qkv, cosT, sinT, qrb, krb, vtb);

  // attention (full-D per batch): QK causal block-skip, PV K-limited
  gemm256<4, 1><<<dim3(64, 1, 2), 512, 0, stream>>>(
      qrb, krb, scoresB, nullptr, 2048, 2048, 8, 0, 64, 4194304, 4194304, 4194304);
  softmax_causal<<<4096, 256, 0, stream>>>(scoresB, probsB);
  gemm256<0, 2><<<dim3(64, 1, 2), 512, 0, stream>>>(
      probsB, vtb, attnb, nullptr, 2048, 2048, 8, 0, 64, 4194304, 4194304, 4194304);

  // O-proj: split-K=2 -> combine with residual
  gemm256<4, 0><<<dim3(128, 1, 2), 512, 0, stream>>>(
      attnb, woq, part, nullptr, 2048, 2048, 8, 1024, 32, 0, 0, 8388608);
  combine2<<<2048, 256, 0, stream>>>(hidden, part, hbuf, 2097152);

  // late quantize: wg, wu
  MArgs ql;
  ql.src[0] = wg; ql.dst[0] = wgq; ql.n[0] = 16777216; ql.sidx[0] = 4;
  ql.src[1] = wu; ql.dst[1] = wuq; ql.n[1] = 16777216; ql.sidx[1] = 5;
  for (int i = 2; i < 7; ++i) { ql.src[i] = wg; ql.dst[i] = nullptr; ql.n[i] = 0; ql.sidx[i] = 0; }
  quantize_multi<<<dim3(2048, 2), 256, 0, stream>>>(ql, scales);

  rmsnorm_k<<<4096, 256, 0, stream>>>(hbuf, ln2, ybuf);

  // G, U: [4096x8192x2048], grid 512, 64 K-chunks
  gemm256<0, 0><<<dim3(512, 1, 1), 512, 0, stream>>>(
      ybuf, wgq, gbuf, nullptr, 8192, 2048, 32, 2048, 64, 0, 0, 0);
  gemm256<2, 0><<<dim3(512, 1, 1), 512, 0, stream>>>(
      ybuf, wuq, gated, gbuf, 8192, 2048, 32, 2048, 64, 0, 0, 0);

  // D: [4096x2048x8192] split-K=2 -> combine into d_out
  gemm256<4, 0><<<dim3(128, 1, 2), 512, 0, stream>>>(
      gated, wdq, part, nullptr, 2048, 8192, 8, 4096, 128, 0, 0, 8388608);
  combine2<<<2048, 256, 0, stream>>>(hbuf, part, (float*)d_out, 2097152);
}

// Round 7
// 898.412 us; speedup vs baseline: 1.0936x; 1.0567x over previous
//
#include <hip/hip_runtime.h>
#include <stdint.h>

#define DEV __device__ __forceinline__

typedef __attribute__((ext_vector_type(8))) short short8;
typedef __attribute__((ext_vector_type(8))) __bf16 bf16x8;
typedef __attribute__((ext_vector_type(4))) float f32x4;

DEV unsigned short f2bf(float f) {
  union { float f; unsigned int u; } v; v.f = f;
  unsigned int r = v.u + 0x7fffu + ((v.u >> 16) & 1u);
  return (unsigned short)(r >> 16);
}
DEV float bf2f(unsigned short h) {
  union { unsigned int u; float f; } v; v.u = ((unsigned int)h) << 16;
  return v.f;
}
DEV f32x4 mfma16(short8 a, short8 b, f32x4 c) {
  return __builtin_amdgcn_mfma_f32_16x16x32_bf16(
      __builtin_bit_cast(bf16x8, a), __builtin_bit_cast(bf16x8, b), c, 0, 0, 0);
}
DEV void gload_lds16(const void* g, void* lds) {
  __builtin_amdgcn_global_load_lds(
      (const __attribute__((address_space(1))) void*)g,
      (__attribute__((address_space(3))) void*)lds, 16, 0, 0);
}

struct MArgs {
  const float* src[7];
  unsigned short* dst[7];
  int n[7];
  int sidx[7];
};

// ---------------- abs-mean partial (all matrices, one launch) ----------------
__global__ __launch_bounds__(256) void absmean_partial_multi(
    MArgs a, float* __restrict__ partial) {
  const int m = blockIdx.y;
  const float4* w4 = (const float4*)a.src[m];
  const int n4 = a.n[m] >> 2;
  float s = 0.f;
  for (int i = blockIdx.x * 256 + threadIdx.x; i < n4; i += 1024 * 256) {
    float4 v = w4[i];
    s += fabsf(v.x) + fabsf(v.y) + fabsf(v.z) + fabsf(v.w);
  }
#pragma unroll
  for (int mm = 1; mm < 64; mm <<= 1) s += __shfl_xor(s, mm);
  __shared__ float red[4];
  if ((threadIdx.x & 63) == 0) red[threadIdx.x >> 6] = s;
  __syncthreads();
  if (threadIdx.x == 0)
    partial[m * 1024 + blockIdx.x] = red[0] + red[1] + red[2] + red[3];
}

__global__ __launch_bounds__(256) void absmean_final(
    const float* __restrict__ partial, float* __restrict__ scales) {
  __shared__ double red[256];
  const int m = blockIdx.x;
  double s = 0.0;
  for (int i = threadIdx.x; i < 1024; i += 256) s += (double)partial[m * 1024 + i];
  red[threadIdx.x] = s;
  __syncthreads();
  for (int t = 128; t > 0; t >>= 1) {
    if (threadIdx.x < t) red[threadIdx.x] += red[threadIdx.x + t];
    __syncthreads();
  }
  if (threadIdx.x == 0) {
    const long long cnt = (m < 4) ? 4194304ll : 16777216ll;
    scales[m] = (float)(red[0] / (double)cnt);
  }
}

// ---------------- ternary quantize -> bf16 (batched) ----------------
__global__ __launch_bounds__(256) void quantize_multi(
    MArgs a, const float* __restrict__ scales) {
  const int m = blockIdx.y;
  const float sc = scales[a.sidx[m]];
  const float inv = 1.f / (sc + 1e-5f);
  const float4* src = (const float4*)a.src[m];
  ushort4* dst = (ushort4*)a.dst[m];
  const int n4 = a.n[m] >> 2;
  for (int i = blockIdx.x * 256 + threadIdx.x; i < n4; i += 2048 * 256) {
    float4 v = src[i];
    ushort4 o;
    o.x = f2bf(fminf(fmaxf(rintf(v.x * inv), -1.f), 1.f) * sc);
    o.y = f2bf(fminf(fmaxf(rintf(v.y * inv), -1.f), 1.f) * sc);
    o.z = f2bf(fminf(fmaxf(rintf(v.z * inv), -1.f), 1.f) * sc);
    o.w = f2bf(fminf(fmaxf(rintf(v.w * inv), -1.f), 1.f) * sc);
    dst[i] = o;
  }
}

// ---------------- RMSNorm (f32 in -> bf16 out) ----------------
__global__ __launch_bounds__(256) void rmsnorm_k(
    const float* __restrict__ x, const float* __restrict__ wt,
    unsigned short* __restrict__ out) {
  const long long t = blockIdx.x;
  const float* xr = x + t * 2048;
  const int i0 = threadIdx.x * 8;
  float4 a = *(const float4*)(xr + i0);
  float4 b = *(const float4*)(xr + i0 + 4);
  float ss = a.x * a.x + a.y * a.y + a.z * a.z + a.w * a.w +
             b.x * b.x + b.y * b.y + b.z * b.z + b.w * b.w;
#pragma unroll
  for (int m = 1; m < 64; m <<= 1) ss += __shfl_xor(ss, m);
  __shared__ float red[4];
  if ((threadIdx.x & 63) == 0) red[threadIdx.x >> 6] = ss;
  __syncthreads();
  float tot = red[0] + red[1] + red[2] + red[3];
  float rs = rsqrtf(tot * (1.f / 2048.f) + 1e-5f);
  float4 wa = *(const float4*)(wt + i0);
  float4 wb = *(const float4*)(wt + i0 + 4);
  ushort4 o1, o2;
  o1.x = f2bf(a.x * wa.x * rs); o1.y = f2bf(a.y * wa.y * rs);
  o1.z = f2bf(a.z * wa.z * rs); o1.w = f2bf(a.w * wa.w * rs);
  o2.x = f2bf(b.x * wb.x * rs); o2.y = f2bf(b.y * wb.y * rs);
  o2.z = f2bf(b.z * wb.z * rs); o2.w = f2bf(b.w * wb.w * rs);
  *(ushort4*)(out + t * 2048 + i0) = o1;
  *(ushort4*)(out + t * 2048 + i0 + 4) = o2;
}

// ---------------- RoPE + V transpose ----------------
__global__ __launch_bounds__(256) void rope_k(
    const unsigned short* __restrict__ qkv, const float* __restrict__ cosT,
    const float* __restrict__ sinT, unsigned short* __restrict__ qr,
    unsigned short* __restrict__ kr, unsigned short* __restrict__ vt) {
  const long long gid = (long long)blockIdx.x * 256 + threadIdx.x;
  const int t = (int)(gid >> 10);
  const int r = (int)(gid & 1023);
  const int h = r >> 6, d = r & 63;
  const int s = t & 2047, b = t >> 11;
  const unsigned short* row = qkv + (long long)t * 6144;
  const float c = cosT[s * 128 + d], sn = sinT[s * 128 + d];
  const int col = h * 128 + d;
  const float SC = 0.08838834764831845f;  // 1/sqrt(128)
  float q1 = bf2f(row[col]), q2 = bf2f(row[col + 64]);
  float k1 = bf2f(row[2048 + col]), k2 = bf2f(row[2048 + col + 64]);
  long long ob = (long long)t * 2048 + col;
  qr[ob] = f2bf((q1 * c - q2 * sn) * SC);
  qr[ob + 64] = f2bf((q2 * c + q1 * sn) * SC);
  kr[ob] = f2bf(k1 * c - k2 * sn);
  kr[ob + 64] = f2bf(k2 * c + k1 * sn);
  vt[((long long)b * 2048 + col) * 2048 + s] = row[4096 + col];
  vt[((long long)b * 2048 + col + 64) * 2048 + s] = row[4096 + col + 64];
}

// ---------------- causal row softmax (single global read, regs) ----------------
__global__ __launch_bounds__(256) void softmax_causal(
    const float* __restrict__ scores, unsigned short* __restrict__ probs) {
  const int r = blockIdx.x;
  const int s = r & 2047;
  const float* src = scores + (long long)r * 2048;
  unsigned short* dst = probs + (long long)r * 2048;
  const int L = s + 1;
  const int j0 = threadIdx.x * 8;
  float4 a = *(const float4*)(src + j0);
  float4 b = *(const float4*)(src + j0 + 4);
  float v[8] = {a.x, a.y, a.z, a.w, b.x, b.y, b.z, b.w};
  float mx = -1e30f;
#pragma unroll
  for (int i = 0; i < 8; ++i) {
    if (j0 + i >= L) v[i] = -1e30f;
    mx = fmaxf(mx, v[i]);
  }
#pragma unroll
  for (int m = 1; m < 64; m <<= 1) mx = fmaxf(mx, __shfl_xor(mx, m));
  __shared__ float redM[4], redS[4];
  if ((threadIdx.x & 63) == 0) redM[threadIdx.x >> 6] = mx;
  __syncthreads();
  mx = fmaxf(fmaxf(redM[0], redM[1]), fmaxf(redM[2], redM[3]));
  float sum = 0.f;
#pragma unroll
  for (int i = 0; i < 8; ++i) {
    v[i] = (j0 + i < L) ? __expf(v[i] - mx) : 0.f;
    sum += v[i];
  }
#pragma unroll
  for (int m = 1; m < 64; m <<= 1) sum += __shfl_xor(sum, m);
  if ((threadIdx.x & 63) == 0) redS[threadIdx.x >> 6] = sum;
  __syncthreads();
  const float inv = 1.f / (redS[0] + redS[1] + redS[2] + redS[3]);
  ushort4 o1, o2;
  o1.x = f2bf(v[0] * inv); o1.y = f2bf(v[1] * inv);
  o1.z = f2bf(v[2] * inv); o1.w = f2bf(v[3] * inv);
  o2.x = f2bf(v[4] * inv); o2.y = f2bf(v[5] * inv);
  o2.z = f2bf(v[6] * inv); o2.w = f2bf(v[7] * inv);
  *(ushort4*)(dst + j0) = o1;
  *(ushort4*)(dst + j0 + 4) = o2;
}

// ---------------- 256^2 NT GEMM: round-4 core (16x16 MFMA, 0-conflict) ----------------
// 8 waves (2Mx4N), wave tile 128x64 as 8m x 4n frags of 16x16.
// BK=32, 4-slot K-chunk ring, counted vmcnt(8), swizzled LDS
// (LDS[r][w] = global[r][w ^ ((r>>1)&3)], rows 64B, 16B windows),
// 2D-brick XCD schedule.
// EPI 0: bf16. 2: bf16 = Ep(bf16)*acc. 4: f32 raw at +z*zCout.
// CAUSAL 0: none. 1: skip 256-blocks with n0 > m0. 2: K-limit ng to (m0+256)/32.
template <int EPI, int CAUSAL>
__global__ __launch_bounds__(512, 2) void gemm256(
    const unsigned short* __restrict__ A, const unsigned short* __restrict__ Bw,
    void* __restrict__ Cp, const void* __restrict__ Ep,
    int N, int K, int nbx, int kLen, int ngTot,
    long long sAz, long long sBz, long long zCout) {
  __shared__ __align__(16) unsigned short lds[4 * 2 * 8192];  // 128KB
  __shared__ __align__(16) unsigned short ldsDummy[512];      // 1KB sink
  const int tid = threadIdx.x;
  const int wid = tid >> 6, l = tid & 63;
  const int wr = wid >> 2, wcn = wid & 3;

  // 2D-brick XCD schedule (4x8 block bricks per 32 consecutive lin ids)
  const int nwg = gridDim.x;  // divisible by 32 (or 64 for attn); nbx div by 8
  const int q8 = nwg >> 3;
  const int lin = (blockIdx.x & 7) * q8 + (blockIdx.x >> 3);
  const int t32 = lin >> 5, r32 = lin & 31;
  const int tpr = nbx >> 3;
  const int tm = t32 / tpr, tn = t32 - tm * tpr;
  const long long m0 = (long long)(tm * 4 + (r32 >> 3)) * 256;
  const long long n0 = (long long)(tn * 8 + (r32 & 7)) * 256;
  if (CAUSAL == 1 && n0 > m0) return;
  const int z = blockIdx.z;
  A += z * sAz;
  Bw += z * sBz;
  const long long kbase = (long long)z * kLen;
  const long long zofs = (long long)z * zCout;
  int ng = ngTot;
  if (CAUSAL == 2) {
    const int lim = (int)((m0 + 256) >> 5);
    ng = lim < ng ? lim : ng;
  }

  // staging (round-4, PMC-verified conflict-free with the 16x16 read below)
  const int stRow = (l >> 2);
  const int stCol = (((l & 3) ^ ((l >> 3) & 3))) * 8;  // pre-swizzled source col
  auto stage = [&](int chunk, int mat) {
    char* base = (char*)lds + (((chunk & 3) * 2 + mat) * 16384);
    const unsigned short* src = mat ? Bw : A;
    const long long rb = mat ? n0 : m0;
    if (chunk < ng) {
      const long long kcol = kbase + (long long)chunk * 32 + stCol;
#pragma unroll
      for (int i = 0; i < 2; ++i) {
        const int row = (wid * 2 + i) * 16 + stRow;
        gload_lds16(&src[(rb + row) * K + kcol], base + (wid * 2 + i) * 1024);
      }
    } else {
#pragma unroll
      for (int i = 0; i < 2; ++i) gload_lds16(&src[rb * K], (char*)ldsDummy);
    }
  };

  // 16x16 frag read (round-4): row = base + (l&15), window = (l>>4) ^ ((row>>1)&3)
  const int ar = l & 15;
  const int rj = ((l >> 4) ^ ((l >> 1) & 3)) << 4;

  f32x4 acc[8][4] = {};

  stage(0, 0); stage(0, 1);
  stage(1, 0); stage(1, 1);
  stage(2, 0); stage(2, 1);
  asm volatile("s_waitcnt vmcnt(8)" ::: "memory");
  __builtin_amdgcn_s_barrier();

  for (int c = 0; c < ng; ++c) {
    const int slot = c & 3;
    const char* sA = (const char*)lds + (slot * 2 + 0) * 16384;
    const char* sB = (const char*)lds + (slot * 2 + 1) * 16384;
    short8 af[4], bf[4];
    // ---- phase 0: m-frags 0-3 ----
#pragma unroll
    for (int m = 0; m < 4; ++m)
      af[m] = *(const short8*)(sA + (wr * 128 + m * 16 + ar) * 64 + rj);
#pragma unroll
    for (int n = 0; n < 4; ++n)
      bf[n] = *(const short8*)(sB + (wcn * 64 + n * 16 + ar) * 64 + rj);
    stage(c + 3, 0);
    __builtin_amdgcn_s_barrier();
    asm volatile("s_waitcnt lgkmcnt(0)" ::: "memory");
    __builtin_amdgcn_sched_barrier(0);
    __builtin_amdgcn_s_setprio(1);
#pragma unroll
    for (int m = 0; m < 4; ++m)
#pragma unroll
      for (int n = 0; n < 4; ++n) acc[m][n] = mfma16(af[m], bf[n], acc[m][n]);
    __builtin_amdgcn_s_setprio(0);
    __builtin_amdgcn_s_barrier();
    // ---- phase 1: m-frags 4-7 (B frags resident) ----
#pragma unroll
    for (int m = 0; m < 4; ++m)
      af[m] = *(const short8*)(sA + (wr * 128 + (m + 4) * 16 + ar) * 64 + rj);
    stage(c + 3, 1);
    __builtin_amdgcn_s_barrier();
    asm volatile("s_waitcnt lgkmcnt(0)" ::: "memory");
    __builtin_amdgcn_sched_barrier(0);
    __builtin_amdgcn_s_setprio(1);
#pragma unroll
    for (int m = 0; m < 4; ++m)
#pragma unroll
      for (int n = 0; n < 4; ++n)
        acc[m + 4][n] = mfma16(af[m], bf[n], acc[m + 4][n]);
    __builtin_amdgcn_s_setprio(0);
    asm volatile("s_waitcnt vmcnt(8)" ::: "memory");
    __builtin_amdgcn_s_barrier();
  }
  asm volatile("s_waitcnt vmcnt(0)" ::: "memory");
  __builtin_amdgcn_s_barrier();

  const int orow = (l >> 4) * 4, ocol = l & 15;
#pragma unroll
  for (int m = 0; m < 8; ++m)
#pragma unroll
    for (int n = 0; n < 4; ++n)
#pragma unroll
      for (int r = 0; r < 4; ++r) {
        const long long gr = m0 + wr * 128 + m * 16 + orow + r;
        const long long gc = n0 + wcn * 64 + n * 16 + ocol;
        const long long idx = zofs + gr * N + gc;
        const float v = acc[m][n][r];
        if (EPI == 0) {
          ((unsigned short*)Cp)[idx] = f2bf(v);
        } else if (EPI == 2) {
          ((unsigned short*)Cp)[idx] = f2bf(bf2f(((const unsigned short*)Ep)[idx]) * v);
        } else {
          ((float*)Cp)[idx] = v;
        }
      }
}

// ---------------- split-K combine ----------------
__global__ __launch_bounds__(256) void combine2(
    const float* __restrict__ ep, const float* __restrict__ p,
    float* __restrict__ out, long long n4) {
  const float4* e4 = (const float4*)ep;
  const float4* p4 = (const float4*)p;
  float4* o4 = (float4*)out;
  for (long long i = blockIdx.x * 256 + threadIdx.x; i < n4; i += 2048 * 256) {
    float4 a = e4[i], b = p4[i], c = p4[i + n4];
    float4 o;
    o.x = a.x + b.x + c.x; o.y = a.y + b.y + c.y;
    o.z = a.z + b.z + c.z; o.w = a.w + b.w + c.w;
    o4[i] = o;
  }
}

extern "C" void kernel_launch(void* const* d_in, const int* in_sizes, int n_in,
                              void* d_out, int out_size, void* d_ws, size_t ws_size,
                              hipStream_t stream) {
  (void)in_sizes; (void)n_in; (void)out_size; (void)ws_size;
  const float* hidden = (const float*)d_in[0];
  const float* cosT = (const float*)d_in[2];
  const float* sinT = (const float*)d_in[3];
  const float* wq = (const float*)d_in[4];
  const float* wk = (const float*)d_in[5];
  const float* wv = (const float*)d_in[6];
  const float* wo = (const float*)d_in[7];
  const float* wg = (const float*)d_in[8];
  const float* wu = (const float*)d_in[9];
  const float* wd = (const float*)d_in[10];
  const float* ln1 = (const float*)d_in[11];
  const float* ln2 = (const float*)d_in[12];

  const size_t MB = 1ull << 20;
  char* ws = (char*)d_ws;
  unsigned short* xn    = (unsigned short*)(ws + 0);        // 16MB
  unsigned short* wqkvq = (unsigned short*)(ws + 16 * MB);  // 24MB
  unsigned short* qkv   = (unsigned short*)(ws + 40 * MB);  // 48MB
  unsigned short* qrb   = (unsigned short*)(ws + 88 * MB);  // 16MB
  unsigned short* krb   = (unsigned short*)(ws + 104 * MB); // 16MB
  unsigned short* vtb   = (unsigned short*)(ws + 120 * MB); // 16MB
  float*          scoresB = (float*)(ws + 0);               // 32MB alias
  unsigned short* probsB  = (unsigned short*)(ws + 40 * MB);// 16MB alias
  float*          part   = (float*)(ws + 0);                // 64MB alias
  unsigned short* wgq   = (unsigned short*)(ws + 0);        // 32MB alias
  unsigned short* wuq   = (unsigned short*)(ws + 32 * MB);  // 32MB alias
  unsigned short* gbuf  = (unsigned short*)(ws + 64 * MB);  // 64MB alias
  unsigned short* attnb = (unsigned short*)(ws + 136 * MB); // 16MB
  unsigned short* woq   = (unsigned short*)(ws + 152 * MB); // 8MB
  float*          hbuf  = (float*)(ws + 160 * MB);          // 32MB
  unsigned short* ybuf  = (unsigned short*)(ws + 192 * MB); // 16MB
  unsigned short* gated = (unsigned short*)(ws + 208 * MB); // 64MB
  unsigned short* wdq   = (unsigned short*)(ws + 272 * MB); // 32MB
  float* wspart         = (float*)(ws + 304 * MB);          // 28KB
  float* scales         = (float*)(ws + 304 * MB + 32768);

  // --- scales ---
  MArgs am;
  am.src[0] = wq; am.src[1] = wk; am.src[2] = wv; am.src[3] = wo;
  am.src[4] = wg; am.src[5] = wu; am.src[6] = wd;
  am.n[0] = am.n[1] = am.n[2] = am.n[3] = 4194304;
  am.n[4] = am.n[5] = am.n[6] = 16777216;
  for (int i = 0; i < 7; ++i) { am.dst[i] = nullptr; am.sidx[i] = i; }
  absmean_partial_multi<<<dim3(1024, 7), 256, 0, stream>>>(am, wspart);
  absmean_final<<<7, 256, 0, stream>>>(wspart, scales);

  // --- early quantize: wq,wk,wv,wo,wd ---
  MArgs qe;
  qe.src[0] = wq; qe.dst[0] = wqkvq;            qe.n[0] = 4194304;  qe.sidx[0] = 0;
  qe.src[1] = wk; qe.dst[1] = wqkvq + 4194304;  qe.n[1] = 4194304;  qe.sidx[1] = 1;
  qe.src[2] = wv; qe.dst[2] = wqkvq + 8388608;  qe.n[2] = 4194304;  qe.sidx[2] = 2;
  qe.src[3] = wo; qe.dst[3] = woq;              qe.n[3] = 4194304;  qe.sidx[3] = 3;
  qe.src[4] = wd; qe.dst[4] = wdq;              qe.n[4] = 16777216; qe.sidx[4] = 6;
  qe.src[5] = wq; qe.dst[5] = nullptr; qe.n[5] = 0; qe.sidx[5] = 0;
  qe.src[6] = wq; qe.dst[6] = nullptr; qe.n[6] = 0; qe.sidx[6] = 0;
  quantize_multi<<<dim3(2048, 5), 256, 0, stream>>>(qe, scales);

  rmsnorm_k<<<4096, 256, 0, stream>>>(hidden, ln1, xn);

  // QKV: [4096x6144x2048], grid 384, 64 K-chunks
  gemm256<0, 0><<<dim3(384, 1, 1), 512, 0, stream>>>(
      xn, wqkvq, qkv, nullptr, 6144, 2048, 24, 2048, 64, 0, 0, 0);

  rope_k<<<16384, 256, 0, stream>>>(qkv, cosT, sinT, qrb, krb, vtb);

  // attention (full-D per batch): QK causal block-skip, PV K-limited
  gemm256<4, 1><<<dim3(64, 1, 2), 512, 0, stream>>>(
      qrb, krb, scoresB, nullptr, 2048, 2048, 8, 0, 64, 4194304, 4194304, 4194304);
  softmax_causal<<<4096, 256, 0, stream>>>(scoresB, probsB);
  gemm256<0, 2><<<dim3(64, 1, 2), 512, 0, stream>>>(
      probsB, vtb, attnb, nullptr, 2048, 2048, 8, 0, 64, 4194304, 4194304, 4194304);

  // O-proj: split-K=2 -> combine with residual
  gemm256<4, 0><<<dim3(128, 1, 2), 512, 0, stream>>>(
      attnb, woq, part, nullptr, 2048, 2048, 8, 1024, 32, 0, 0, 8388608);
  combine2<<<2048, 256, 0, stream>>>(hidden, part, hbuf, 2097152);

  // late quantize: wg, wu
  MArgs ql;
  ql.src[0] = wg; ql.dst[0] = wgq; ql.n[0] = 16777216; ql.sidx[0] = 4;
  ql.src[1] = wu; ql.dst[1] = wuq; ql.n[1] = 16777216; ql.sidx[1] = 5;
  for (int i = 2; i < 7; ++i) { ql.src[i] = wg; ql.dst[i] = nullptr; ql.n[i] = 0; ql.sidx[i] = 0; }
  quantize_multi<<<dim3(2048, 2), 256, 0, stream>>>(ql, scales);

  rmsnorm_k<<<4096, 256, 0, stream>>>(hbuf, ln2, ybuf);

  // G, U: [4096x8192x2048], grid 512, 64 K-chunks
  gemm256<0, 0><<<dim3(512, 1, 1), 512, 0, stream>>>(
      ybuf, wgq, gbuf, nullptr, 8192, 2048, 32, 2048, 64, 0, 0, 0);
  gemm256<2, 0><<<dim3(512, 1, 1), 512, 0, stream>>>(
      ybuf, wuq, gated, gbuf, 8192, 2048, 32, 2048, 64, 0, 0, 0);

  // D: [4096x2048x8192] split-K=2 -> combine into d_out
  gemm256<4, 0><<<dim3(128, 1, 2), 512, 0, stream>>>(
      gated, wdq, part, nullptr, 2048, 8192, 8, 4096, 128, 0, 0, 8388608);
  combine2<<<2048, 256, 0, stream>>>(hbuf, part, (float*)d_out, 2097152);
}

// Round 8
// 825.705 us; speedup vs baseline: 1.1899x; 1.0881x over previous
//
#include <hip/hip_runtime.h>
#include <stdint.h>

#define DEV __device__ __forceinline__

typedef __attribute__((ext_vector_type(8))) short short8;
typedef __attribute__((ext_vector_type(8))) __bf16 bf16x8;
typedef __attribute__((ext_vector_type(4))) float f32x4;

DEV unsigned short f2bf(float f) {
  union { float f; unsigned int u; } v; v.f = f;
  unsigned int r = v.u + 0x7fffu + ((v.u >> 16) & 1u);
  return (unsigned short)(r >> 16);
}
DEV float bf2f(unsigned short h) {
  union { unsigned int u; float f; } v; v.u = ((unsigned int)h) << 16;
  return v.f;
}
DEV f32x4 mfma16(short8 a, short8 b, f32x4 c) {
  return __builtin_amdgcn_mfma_f32_16x16x32_bf16(
      __builtin_bit_cast(bf16x8, a), __builtin_bit_cast(bf16x8, b), c, 0, 0, 0);
}
DEV void gload_lds16(const void* g, void* lds) {
  __builtin_amdgcn_global_load_lds(
      (const __attribute__((address_space(1))) void*)g,
      (__attribute__((address_space(3))) void*)lds, 16, 0, 0);
}

struct MArgs {
  const float* src[7];
  unsigned short* dst[7];
  int n[7];
  int sidx[7];
};

// ---------------- abs-mean partial (all matrices, one launch) ----------------
__global__ __launch_bounds__(256) void absmean_partial_multi(
    MArgs a, float* __restrict__ partial) {
  const int m = blockIdx.y;
  const float4* w4 = (const float4*)a.src[m];
  const int n4 = a.n[m] >> 2;
  float s = 0.f;
  for (int i = blockIdx.x * 256 + threadIdx.x; i < n4; i += 1024 * 256) {
    float4 v = w4[i];
    s += fabsf(v.x) + fabsf(v.y) + fabsf(v.z) + fabsf(v.w);
  }
#pragma unroll
  for (int mm = 1; mm < 64; mm <<= 1) s += __shfl_xor(s, mm);
  __shared__ float red[4];
  if ((threadIdx.x & 63) == 0) red[threadIdx.x >> 6] = s;
  __syncthreads();
  if (threadIdx.x == 0)
    partial[m * 1024 + blockIdx.x] = red[0] + red[1] + red[2] + red[3];
}

__global__ __launch_bounds__(256) void absmean_final(
    const float* __restrict__ partial, float* __restrict__ scales) {
  __shared__ double red[256];
  const int m = blockIdx.x;
  double s = 0.0;
  for (int i = threadIdx.x; i < 1024; i += 256) s += (double)partial[m * 1024 + i];
  red[threadIdx.x] = s;
  __syncthreads();
  for (int t = 128; t > 0; t >>= 1) {
    if (threadIdx.x < t) red[threadIdx.x] += red[threadIdx.x + t];
    __syncthreads();
  }
  if (threadIdx.x == 0) {
    const long long cnt = (m < 4) ? 4194304ll : 16777216ll;
    scales[m] = (float)(red[0] / (double)cnt);
  }
}

// ---------------- ternary quantize -> bf16 (batched) ----------------
__global__ __launch_bounds__(256) void quantize_multi(
    MArgs a, const float* __restrict__ scales) {
  const int m = blockIdx.y;
  const float sc = scales[a.sidx[m]];
  const float inv = 1.f / (sc + 1e-5f);
  const float4* src = (const float4*)a.src[m];
  ushort4* dst = (ushort4*)a.dst[m];
  const int n4 = a.n[m] >> 2;
  for (int i = blockIdx.x * 256 + threadIdx.x; i < n4; i += 2048 * 256) {
    float4 v = src[i];
    ushort4 o;
    o.x = f2bf(fminf(fmaxf(rintf(v.x * inv), -1.f), 1.f) * sc);
    o.y = f2bf(fminf(fmaxf(rintf(v.y * inv), -1.f), 1.f) * sc);
    o.z = f2bf(fminf(fmaxf(rintf(v.z * inv), -1.f), 1.f) * sc);
    o.w = f2bf(fminf(fmaxf(rintf(v.w * inv), -1.f), 1.f) * sc);
    dst[i] = o;
  }
}

// ---------------- RMSNorm (f32 in -> bf16 out) ----------------
__global__ __launch_bounds__(256) void rmsnorm_k(
    const float* __restrict__ x, const float* __restrict__ wt,
    unsigned short* __restrict__ out) {
  const long long t = blockIdx.x;
  const float* xr = x + t * 2048;
  const int i0 = threadIdx.x * 8;
  float4 a = *(const float4*)(xr + i0);
  float4 b = *(const float4*)(xr + i0 + 4);
  float ss = a.x * a.x + a.y * a.y + a.z * a.z + a.w * a.w +
             b.x * b.x + b.y * b.y + b.z * b.z + b.w * b.w;
#pragma unroll
  for (int m = 1; m < 64; m <<= 1) ss += __shfl_xor(ss, m);
  __shared__ float red[4];
  if ((threadIdx.x & 63) == 0) red[threadIdx.x >> 6] = ss;
  __syncthreads();
  float tot = red[0] + red[1] + red[2] + red[3];
  float rs = rsqrtf(tot * (1.f / 2048.f) + 1e-5f);
  float4 wa = *(const float4*)(wt + i0);
  float4 wb = *(const float4*)(wt + i0 + 4);
  ushort4 o1, o2;
  o1.x = f2bf(a.x * wa.x * rs); o1.y = f2bf(a.y * wa.y * rs);
  o1.z = f2bf(a.z * wa.z * rs); o1.w = f2bf(a.w * wa.w * rs);
  o2.x = f2bf(b.x * wb.x * rs); o2.y = f2bf(b.y * wb.y * rs);
  o2.z = f2bf(b.z * wb.z * rs); o2.w = f2bf(b.w * wb.w * rs);
  *(ushort4*)(out + t * 2048 + i0) = o1;
  *(ushort4*)(out + t * 2048 + i0 + 4) = o2;
}

// ---------------- RoPE + V transpose ----------------
__global__ __launch_bounds__(256) void rope_k(
    const unsigned short* __restrict__ qkv, const float* __restrict__ cosT,
    const float* __restrict__ sinT, unsigned short* __restrict__ qr,
    unsigned short* __restrict__ kr, unsigned short* __restrict__ vt) {
  const long long gid = (long long)blockIdx.x * 256 + threadIdx.x;
  const int t = (int)(gid >> 10);
  const int r = (int)(gid & 1023);
  const int h = r >> 6, d = r & 63;
  const int s = t & 2047, b = t >> 11;
  const unsigned short* row = qkv + (long long)t * 6144;
  const float c = cosT[s * 128 + d], sn = sinT[s * 128 + d];
  const int col = h * 128 + d;
  const float SC = 0.08838834764831845f;  // 1/sqrt(128)
  float q1 = bf2f(row[col]), q2 = bf2f(row[col + 64]);
  float k1 = bf2f(row[2048 + col]), k2 = bf2f(row[2048 + col + 64]);
  long long ob = (long long)t * 2048 + col;
  qr[ob] = f2bf((q1 * c - q2 * sn) * SC);
  qr[ob + 64] = f2bf((q2 * c + q1 * sn) * SC);
  kr[ob] = f2bf(k1 * c - k2 * sn);
  kr[ob + 64] = f2bf(k2 * c + k1 * sn);
  vt[((long long)b * 2048 + col) * 2048 + s] = row[4096 + col];
  vt[((long long)b * 2048 + col + 64) * 2048 + s] = row[4096 + col + 64];
}

// ---------------- causal row softmax (single global read, regs) ----------------
__global__ __launch_bounds__(256) void softmax_causal(
    const float* __restrict__ scores, unsigned short* __restrict__ probs) {
  const int r = blockIdx.x;
  const int s = r & 2047;
  const float* src = scores + (long long)r * 2048;
  unsigned short* dst = probs + (long long)r * 2048;
  const int L = s + 1;
  const int j0 = threadIdx.x * 8;
  float4 a = *(const float4*)(src + j0);
  float4 b = *(const float4*)(src + j0 + 4);
  float v[8] = {a.x, a.y, a.z, a.w, b.x, b.y, b.z, b.w};
  float mx = -1e30f;
#pragma unroll
  for (int i = 0; i < 8; ++i) {
    if (j0 + i >= L) v[i] = -1e30f;
    mx = fmaxf(mx, v[i]);
  }
#pragma unroll
  for (int m = 1; m < 64; m <<= 1) mx = fmaxf(mx, __shfl_xor(mx, m));
  __shared__ float redM[4], redS[4];
  if ((threadIdx.x & 63) == 0) redM[threadIdx.x >> 6] = mx;
  __syncthreads();
  mx = fmaxf(fmaxf(redM[0], redM[1]), fmaxf(redM[2], redM[3]));
  float sum = 0.f;
#pragma unroll
  for (int i = 0; i < 8; ++i) {
    v[i] = (j0 + i < L) ? __expf(v[i] - mx) : 0.f;
    sum += v[i];
  }
#pragma unroll
  for (int m = 1; m < 64; m <<= 1) sum += __shfl_xor(sum, m);
  if ((threadIdx.x & 63) == 0) redS[threadIdx.x >> 6] = sum;
  __syncthreads();
  const float inv = 1.f / (redS[0] + redS[1] + redS[2] + redS[3]);
  ushort4 o1, o2;
  o1.x = f2bf(v[0] * inv); o1.y = f2bf(v[1] * inv);
  o1.z = f2bf(v[2] * inv); o1.w = f2bf(v[3] * inv);
  o2.x = f2bf(v[4] * inv); o2.y = f2bf(v[5] * inv);
  o2.z = f2bf(v[6] * inv); o2.w = f2bf(v[7] * inv);
  *(ushort4*)(dst + j0) = o1;
  *(ushort4*)(dst + j0 + 4) = o2;
}

// ---------------- 256^2 NT GEMM: pipelined K-loop (reads 1 phase ahead) ------
// 8 waves (2Mx4N), wave tile 128x64 as 8m x 4n frags of 16x16.
// BK=32, 4-slot ring, swizzled LDS (verified 0-conflict), brick schedule.
// Per chunk: p0 {read A4-7(cur), stage(c+3 both mats), MFMA A0-3xB},
//            p1 {vmcnt(8)+barrier, read A0-3+B(next slot), MFMA A4-7xB}.
// One barrier/chunk. Compiler inserts counted lgkm waits before each MFMA.
// Slot overwrite safety: a slot's last ds_reads are issued >=1 phase before the
// rendezvous barrier (latency ~120cy, done by barrier); the overwriting
// gload_lds is issued >=1 MFMA-cluster after that barrier and lands ~400cy
// later -> ~700cy margin.
// EPI 0: bf16. 2: bf16 = Ep(bf16)*acc. 4: f32 raw at +z*zCout.
// CAUSAL 0: none. 1: skip 256-blocks with n0 > m0. 2: K-limit ng to (m0+256)/32.
template <int EPI, int CAUSAL>
__global__ __launch_bounds__(512, 2) void gemm256(
    const unsigned short* __restrict__ A, const unsigned short* __restrict__ Bw,
    void* __restrict__ Cp, const void* __restrict__ Ep,
    int N, int K, int nbx, int kLen, int ngTot,
    long long sAz, long long sBz, long long zCout) {
  __shared__ __align__(16) unsigned short lds[4 * 2 * 8192];  // 128KB
  __shared__ __align__(16) unsigned short ldsDummy[512];      // 1KB sink
  const int tid = threadIdx.x;
  const int wid = tid >> 6, l = tid & 63;
  const int wr = wid >> 2, wcn = wid & 3;

  // 2D-brick XCD schedule (4x8 block bricks per 32 consecutive lin ids)
  const int nwg = gridDim.x;
  const int q8 = nwg >> 3;
  const int lin = (blockIdx.x & 7) * q8 + (blockIdx.x >> 3);
  const int t32 = lin >> 5, r32 = lin & 31;
  const int tpr = nbx >> 3;
  const int tm = t32 / tpr, tn = t32 - tm * tpr;
  const long long m0 = (long long)(tm * 4 + (r32 >> 3)) * 256;
  const long long n0 = (long long)(tn * 8 + (r32 & 7)) * 256;
  if (CAUSAL == 1 && n0 > m0) return;
  const int z = blockIdx.z;
  A += z * sAz;
  Bw += z * sBz;
  const long long kbase = (long long)z * kLen;
  const long long zofs = (long long)z * zCout;
  int ng = ngTot;
  if (CAUSAL == 2) {
    const int lim = (int)((m0 + 256) >> 5);
    ng = lim < ng ? lim : ng;
  }

  // staging: both matrices of one chunk (4 loads/thread)
  const int stRow = (l >> 2);
  const int stCol = (((l & 3) ^ ((l >> 3) & 3))) * 8;  // pre-swizzled source col
  auto stage = [&](int chunk) {
    if (chunk < ng) {
      char* base = (char*)lds + ((chunk & 3) * 2) * 16384;
      const long long kcol = kbase + (long long)chunk * 32 + stCol;
#pragma unroll
      for (int i = 0; i < 2; ++i) {
        const int row = (wid * 2 + i) * 16 + stRow;
        gload_lds16(&A[(m0 + row) * K + kcol], base + (wid * 2 + i) * 1024);
        gload_lds16(&Bw[(n0 + row) * K + kcol],
                    base + 16384 + (wid * 2 + i) * 1024);
      }
    } else {
#pragma unroll
      for (int i = 0; i < 4; ++i) gload_lds16(&A[m0 * K], (char*)ldsDummy);
    }
  };

  // 16x16 frag read: row = base + (l&15), window = (l>>4) ^ ((row>>1)&3)
  const int ar = l & 15;
  const int rj = ((l >> 4) ^ ((l >> 1) & 3)) << 4;

  auto readA03 = [&](int slot, short8 (&a)[4]) {
    const char* sA = (const char*)lds + (slot * 2) * 16384;
#pragma unroll
    for (int m = 0; m < 4; ++m)
      a[m] = *(const short8*)(sA + (wr * 128 + m * 16 + ar) * 64 + rj);
  };
  auto readA47 = [&](int slot, short8 (&a)[4]) {
    const char* sA = (const char*)lds + (slot * 2) * 16384;
#pragma unroll
    for (int m = 0; m < 4; ++m)
      a[m] = *(const short8*)(sA + (wr * 128 + (m + 4) * 16 + ar) * 64 + rj);
  };
  auto readB = [&](int slot, short8 (&b)[4]) {
    const char* sB = (const char*)lds + (slot * 2 + 1) * 16384;
#pragma unroll
    for (int n = 0; n < 4; ++n)
      b[n] = *(const short8*)(sB + (wcn * 64 + n * 16 + ar) * 64 + rj);
  };

  f32x4 acc[8][4] = {};
  short8 aX[4], bX[4], aY[4], bY[4], a47[4];

  stage(0); stage(1); stage(2);
  asm volatile("s_waitcnt vmcnt(8)" ::: "memory");
  __builtin_amdgcn_s_barrier();
  readA03(0, aX);
  readB(0, bX);

  auto chunkBody = [&](int c, short8 (&cur03)[4], short8 (&curB)[4],
                       short8 (&nxt03)[4], short8 (&nxtB)[4]) {
    const int slot = c & 3;
    // ---- phase 0 ----
    readA47(slot, a47);
    stage(c + 3);
    __builtin_amdgcn_s_setprio(1);
#pragma unroll
    for (int m = 0; m < 4; ++m)
#pragma unroll
      for (int n = 0; n < 4; ++n)
        acc[m][n] = mfma16(cur03[m], curB[n], acc[m][n]);
    __builtin_amdgcn_s_setprio(0);
    // ---- phase 1 ----
    asm volatile("s_waitcnt vmcnt(8)" ::: "memory");  // chunk c+1 landed
    __builtin_amdgcn_s_barrier();
    readA03((c + 1) & 3, nxt03);
    readB((c + 1) & 3, nxtB);
    __builtin_amdgcn_s_setprio(1);
#pragma unroll
    for (int m = 0; m < 4; ++m)
#pragma unroll
      for (int n = 0; n < 4; ++n)
        acc[m + 4][n] = mfma16(a47[m], curB[n], acc[m + 4][n]);
    __builtin_amdgcn_s_setprio(0);
  };

  for (int c = 0; c < ng; c += 2) {
    chunkBody(c, aX, bX, aY, bY);
    chunkBody(c + 1, aY, bY, aX, bX);
  }
  asm volatile("s_waitcnt vmcnt(0)" ::: "memory");
  __builtin_amdgcn_s_barrier();

  const int orow = (l >> 4) * 4, ocol = l & 15;
#pragma unroll
  for (int m = 0; m < 8; ++m)
#pragma unroll
    for (int n = 0; n < 4; ++n)
#pragma unroll
      for (int r = 0; r < 4; ++r) {
        const long long gr = m0 + wr * 128 + m * 16 + orow + r;
        const long long gc = n0 + wcn * 64 + n * 16 + ocol;
        const long long idx = zofs + gr * N + gc;
        const float v = acc[m][n][r];
        if (EPI == 0) {
          ((unsigned short*)Cp)[idx] = f2bf(v);
        } else if (EPI == 2) {
          ((unsigned short*)Cp)[idx] = f2bf(bf2f(((const unsigned short*)Ep)[idx]) * v);
        } else {
          ((float*)Cp)[idx] = v;
        }
      }
}

// ---------------- split-K combine ----------------
__global__ __launch_bounds__(256) void combine2(
    const float* __restrict__ ep, const float* __restrict__ p,
    float* __restrict__ out, long long n4) {
  const float4* e4 = (const float4*)ep;
  const float4* p4 = (const float4*)p;
  float4* o4 = (float4*)out;
  for (long long i = blockIdx.x * 256 + threadIdx.x; i < n4; i += 2048 * 256) {
    float4 a = e4[i], b = p4[i], c = p4[i + n4];
    float4 o;
    o.x = a.x + b.x + c.x; o.y = a.y + b.y + c.y;
    o.z = a.z + b.z + c.z; o.w = a.w + b.w + c.w;
    o4[i] = o;
  }
}

extern "C" void kernel_launch(void* const* d_in, const int* in_sizes, int n_in,
                              void* d_out, int out_size, void* d_ws, size_t ws_size,
                              hipStream_t stream) {
  (void)in_sizes; (void)n_in; (void)out_size; (void)ws_size;
  const float* hidden = (const float*)d_in[0];
  const float* cosT = (const float*)d_in[2];
  const float* sinT = (const float*)d_in[3];
  const float* wq = (const float*)d_in[4];
  const float* wk = (const float*)d_in[5];
  const float* wv = (const float*)d_in[6];
  const float* wo = (const float*)d_in[7];
  const float* wg = (const float*)d_in[8];
  const float* wu = (const float*)d_in[9];
  const float* wd = (const float*)d_in[10];
  const float* ln1 = (const float*)d_in[11];
  const float* ln2 = (const float*)d_in[12];

  const size_t MB = 1ull << 20;
  char* ws = (char*)d_ws;
  unsigned short* xn    = (unsigned short*)(ws + 0);        // 16MB
  unsigned short* wqkvq = (unsigned short*)(ws + 16 * MB);  // 24MB
  unsigned short* qkv   = (unsigned short*)(ws + 40 * MB);  // 48MB
  unsigned short* qrb   = (unsigned short*)(ws + 88 * MB);  // 16MB
  unsigned short* krb   = (unsigned short*)(ws + 104 * MB); // 16MB
  unsigned short* vtb   = (unsigned short*)(ws + 120 * MB); // 16MB
  float*          scoresB = (float*)(ws + 0);               // 32MB alias
  unsigned short* probsB  = (unsigned short*)(ws + 40 * MB);// 16MB alias
  float*          part   = (float*)(ws + 0);                // 64MB alias
  unsigned short* wgq   = (unsigned short*)(ws + 0);        // 32MB alias
  unsigned short* wuq   = (unsigned short*)(ws + 32 * MB);  // 32MB alias
  unsigned short* gbuf  = (unsigned short*)(ws + 64 * MB);  // 64MB alias
  unsigned short* attnb = (unsigned short*)(ws + 136 * MB); // 16MB
  unsigned short* woq   = (unsigned short*)(ws + 152 * MB); // 8MB
  float*          hbuf  = (float*)(ws + 160 * MB);          // 32MB
  unsigned short* ybuf  = (unsigned short*)(ws + 192 * MB); // 16MB
  unsigned short* gated = (unsigned short*)(ws + 208 * MB); // 64MB
  unsigned short* wdq   = (unsigned short*)(ws + 272 * MB); // 32MB
  float* wspart         = (float*)(ws + 304 * MB);          // 28KB
  float* scales         = (float*)(ws + 304 * MB + 32768);

  // --- scales ---
  MArgs am;
  am.src[0] = wq; am.src[1] = wk; am.src[2] = wv; am.src[3] = wo;
  am.src[4] = wg; am.src[5] = wu; am.src[6] = wd;
  am.n[0] = am.n[1] = am.n[2] = am.n[3] = 4194304;
  am.n[4] = am.n[5] = am.n[6] = 16777216;
  for (int i = 0; i < 7; ++i) { am.dst[i] = nullptr; am.sidx[i] = i; }
  absmean_partial_multi<<<dim3(1024, 7), 256, 0, stream>>>(am, wspart);
  absmean_final<<<7, 256, 0, stream>>>(wspart, scales);

  // --- early quantize: wq,wk,wv,wo,wd ---
  MArgs qe;
  qe.src[0] = wq; qe.dst[0] = wqkvq;            qe.n[0] = 4194304;  qe.sidx[0] = 0;
  qe.src[1] = wk; qe.dst[1] = wqkvq + 4194304;  qe.n[1] = 4194304;  qe.sidx[1] = 1;
  qe.src[2] = wv; qe.dst[2] = wqkvq + 8388608;  qe.n[2] = 4194304;  qe.sidx[2] = 2;
  qe.src[3] = wo; qe.dst[3] = woq;              qe.n[3] = 4194304;  qe.sidx[3] = 3;
  qe.src[4] = wd; qe.dst[4] = wdq;              qe.n[4] = 16777216; qe.sidx[4] = 6;
  qe.src[5] = wq; qe.dst[5] = nullptr; qe.n[5] = 0; qe.sidx[5] = 0;
  qe.src[6] = wq; qe.dst[6] = nullptr; qe.n[6] = 0; qe.sidx[6] = 0;
  quantize_multi<<<dim3(2048, 5), 256, 0, stream>>>(qe, scales);

  rmsnorm_k<<<4096, 256, 0, stream>>>(hidden, ln1, xn);

  // QKV: [4096x6144x2048], grid 384, 64 K-chunks
  gemm256<0, 0><<<dim3(384, 1, 1), 512, 0, stream>>>(
      xn, wqkvq, qkv, nullptr, 6144, 2048, 24, 2048, 64, 0, 0, 0);

  rope_k<<<16384, 256, 0, stream>>>(qkv, cosT, sinT, qrb, krb, vtb);

  // attention (full-D per batch): QK causal block-skip, PV K-limited
  gemm256<4, 1><<<dim3(64, 1, 2), 512, 0, stream>>>(
      qrb, krb, scoresB, nullptr, 2048, 2048, 8, 0, 64, 4194304, 4194304, 4194304);
  softmax_causal<<<4096, 256, 0, stream>>>(scoresB, probsB);
  gemm256<0, 2><<<dim3(64, 1, 2), 512, 0, stream>>>(
      probsB, vtb, attnb, nullptr, 2048, 2048, 8, 0, 64, 4194304, 4194304, 4194304);

  // O-proj: split-K=2 -> combine with residual
  gemm256<4, 0><<<dim3(128, 1, 2), 512, 0, stream>>>(
      attnb, woq, part, nullptr, 2048, 2048, 8, 1024, 32, 0, 0, 8388608);
  combine2<<<2048, 256, 0, stream>>>(hidden, part, hbuf, 2097152);

  // late quantize: wg, wu
  MArgs ql;
  ql.src[0] = wg; ql.dst[0] = wgq; ql.n[0] = 16777216; ql.sidx[0] = 4;
  ql.src[1] = wu; ql.dst[1] = wuq; ql.n[1] = 16777216; ql.sidx[1] = 5;
  for (int i = 2; i < 7; ++i) { ql.src[i] = wg; ql.dst[i] = nullptr; ql.n[i] = 0; ql.sidx[i] = 0; }
  quantize_multi<<<dim3(2048, 2), 256, 0, stream>>>(ql, scales);

  rmsnorm_k<<<4096, 256, 0, stream>>>(hbuf, ln2, ybuf);

  // G, U: [4096x8192x2048], grid 512, 64 K-chunks
  gemm256<0, 0><<<dim3(512, 1, 1), 512, 0, stream>>>(
      ybuf, wgq, gbuf, nullptr, 8192, 2048, 32, 2048, 64, 0, 0, 0);
  gemm256<2, 0><<<dim3(512, 1, 1), 512, 0, stream>>>(
      ybuf, wuq, gated, gbuf, 8192, 2048, 32, 2048, 64, 0, 0, 0);

  // D: [4096x2048x8192] split-K=2 -> combine into d_out
  gemm256<4, 0><<<dim3(128, 1, 2), 512, 0, stream>>>(
      gated, wdq, part, nullptr, 2048, 8192, 8, 4096, 128, 0, 0, 8388608);
  combine2<<<2048, 256, 0, stream>>>(hbuf, part, (float*)d_out, 2097152);
}

// Round 9
// 824.811 us; speedup vs baseline: 1.1912x; 1.0011x over previous
//
#include <hip/hip_runtime.h>
#include <stdint.h>

#define DEV __device__ __forceinline__

typedef __attribute__((ext_vector_type(8))) short short8;
typedef __attribute__((ext_vector_type(8))) __bf16 bf16x8;
typedef __attribute__((ext_vector_type(4))) float f32x4;

DEV unsigned short f2bf(float f) {
  union { float f; unsigned int u; } v; v.f = f;
  unsigned int r = v.u + 0x7fffu + ((v.u >> 16) & 1u);
  return (unsigned short)(r >> 16);
}
DEV float bf2f(unsigned short h) {
  union { unsigned int u; float f; } v; v.u = ((unsigned int)h) << 16;
  return v.f;
}
DEV f32x4 mfma16(short8 a, short8 b, f32x4 c) {
  return __builtin_amdgcn_mfma_f32_16x16x32_bf16(
      __builtin_bit_cast(bf16x8, a), __builtin_bit_cast(bf16x8, b), c, 0, 0, 0);
}
DEV void gload_lds16(const void* g, void* lds) {
  __builtin_amdgcn_global_load_lds(
      (const __attribute__((address_space(1))) void*)g,
      (__attribute__((address_space(3))) void*)lds, 16, 0, 0);
}

struct MArgs {
  const float* src[7];
  unsigned short* dst[7];
  int n[7];
  int sidx[7];
};

// ---------------- abs-mean partial (all matrices, one launch) ----------------
__global__ __launch_bounds__(256) void absmean_partial_multi(
    MArgs a, float* __restrict__ partial) {
  const int m = blockIdx.y;
  const float4* w4 = (const float4*)a.src[m];
  const int n4 = a.n[m] >> 2;
  float s = 0.f;
  for (int i = blockIdx.x * 256 + threadIdx.x; i < n4; i += 1024 * 256) {
    float4 v = w4[i];
    s += fabsf(v.x) + fabsf(v.y) + fabsf(v.z) + fabsf(v.w);
  }
#pragma unroll
  for (int mm = 1; mm < 64; mm <<= 1) s += __shfl_xor(s, mm);
  __shared__ float red[4];
  if ((threadIdx.x & 63) == 0) red[threadIdx.x >> 6] = s;
  __syncthreads();
  if (threadIdx.x == 0)
    partial[m * 1024 + blockIdx.x] = red[0] + red[1] + red[2] + red[3];
}

__global__ __launch_bounds__(256) void absmean_final(
    const float* __restrict__ partial, float* __restrict__ scales) {
  __shared__ double red[256];
  const int m = blockIdx.x;
  double s = 0.0;
  for (int i = threadIdx.x; i < 1024; i += 256) s += (double)partial[m * 1024 + i];
  red[threadIdx.x] = s;
  __syncthreads();
  for (int t = 128; t > 0; t >>= 1) {
    if (threadIdx.x < t) red[threadIdx.x] += red[threadIdx.x + t];
    __syncthreads();
  }
  if (threadIdx.x == 0) {
    const long long cnt = (m < 4) ? 4194304ll : 16777216ll;
    scales[m] = (float)(red[0] / (double)cnt);
  }
}

// ---------------- ternary quantize -> bf16 (batched) ----------------
__global__ __launch_bounds__(256) void quantize_multi(
    MArgs a, const float* __restrict__ scales) {
  const int m = blockIdx.y;
  const float sc = scales[a.sidx[m]];
  const float inv = 1.f / (sc + 1e-5f);
  const float4* src = (const float4*)a.src[m];
  ushort4* dst = (ushort4*)a.dst[m];
  const int n4 = a.n[m] >> 2;
  for (int i = blockIdx.x * 256 + threadIdx.x; i < n4; i += 2048 * 256) {
    float4 v = src[i];
    ushort4 o;
    o.x = f2bf(fminf(fmaxf(rintf(v.x * inv), -1.f), 1.f) * sc);
    o.y = f2bf(fminf(fmaxf(rintf(v.y * inv), -1.f), 1.f) * sc);
    o.z = f2bf(fminf(fmaxf(rintf(v.z * inv), -1.f), 1.f) * sc);
    o.w = f2bf(fminf(fmaxf(rintf(v.w * inv), -1.f), 1.f) * sc);
    dst[i] = o;
  }
}

// ---------------- RMSNorm (f32 in -> bf16 out) ----------------
__global__ __launch_bounds__(256) void rmsnorm_k(
    const float* __restrict__ x, const float* __restrict__ wt,
    unsigned short* __restrict__ out) {
  const long long t = blockIdx.x;
  const float* xr = x + t * 2048;
  const int i0 = threadIdx.x * 8;
  float4 a = *(const float4*)(xr + i0);
  float4 b = *(const float4*)(xr + i0 + 4);
  float ss = a.x * a.x + a.y * a.y + a.z * a.z + a.w * a.w +
             b.x * b.x + b.y * b.y + b.z * b.z + b.w * b.w;
#pragma unroll
  for (int m = 1; m < 64; m <<= 1) ss += __shfl_xor(ss, m);
  __shared__ float red[4];
  if ((threadIdx.x & 63) == 0) red[threadIdx.x >> 6] = ss;
  __syncthreads();
  float tot = red[0] + red[1] + red[2] + red[3];
  float rs = rsqrtf(tot * (1.f / 2048.f) + 1e-5f);
  float4 wa = *(const float4*)(wt + i0);
  float4 wb = *(const float4*)(wt + i0 + 4);
  ushort4 o1, o2;
  o1.x = f2bf(a.x * wa.x * rs); o1.y = f2bf(a.y * wa.y * rs);
  o1.z = f2bf(a.z * wa.z * rs); o1.w = f2bf(a.w * wa.w * rs);
  o2.x = f2bf(b.x * wb.x * rs); o2.y = f2bf(b.y * wb.y * rs);
  o2.z = f2bf(b.z * wb.z * rs); o2.w = f2bf(b.w * wb.w * rs);
  *(ushort4*)(out + t * 2048 + i0) = o1;
  *(ushort4*)(out + t * 2048 + i0 + 4) = o2;
}

// ---------------- RoPE + V transpose ----------------
__global__ __launch_bounds__(256) void rope_k(
    const unsigned short* __restrict__ qkv, const float* __restrict__ cosT,
    const float* __restrict__ sinT, unsigned short* __restrict__ qr,
    unsigned short* __restrict__ kr, unsigned short* __restrict__ vt) {
  const long long gid = (long long)blockIdx.x * 256 + threadIdx.x;
  const int t = (int)(gid >> 10);
  const int r = (int)(gid & 1023);
  const int h = r >> 6, d = r & 63;
  const int s = t & 2047, b = t >> 11;
  const unsigned short* row = qkv + (long long)t * 6144;
  const float c = cosT[s * 128 + d], sn = sinT[s * 128 + d];
  const int col = h * 128 + d;
  const float SC = 0.08838834764831845f;  // 1/sqrt(128)
  float q1 = bf2f(row[col]), q2 = bf2f(row[col + 64]);
  float k1 = bf2f(row[2048 + col]), k2 = bf2f(row[2048 + col + 64]);
  long long ob = (long long)t * 2048 + col;
  qr[ob] = f2bf((q1 * c - q2 * sn) * SC);
  qr[ob + 64] = f2bf((q2 * c + q1 * sn) * SC);
  kr[ob] = f2bf(k1 * c - k2 * sn);
  kr[ob + 64] = f2bf(k2 * c + k1 * sn);
  vt[((long long)b * 2048 + col) * 2048 + s] = row[4096 + col];
  vt[((long long)b * 2048 + col + 64) * 2048 + s] = row[4096 + col + 64];
}

// ---------------- causal row softmax (single global read, regs) ----------------
__global__ __launch_bounds__(256) void softmax_causal(
    const float* __restrict__ scores, unsigned short* __restrict__ probs) {
  const int r = blockIdx.x;
  const int s = r & 2047;
  const float* src = scores + (long long)r * 2048;
  unsigned short* dst = probs + (long long)r * 2048;
  const int L = s + 1;
  const int j0 = threadIdx.x * 8;
  float4 a = *(const float4*)(src + j0);
  float4 b = *(const float4*)(src + j0 + 4);
  float v[8] = {a.x, a.y, a.z, a.w, b.x, b.y, b.z, b.w};
  float mx = -1e30f;
#pragma unroll
  for (int i = 0; i < 8; ++i) {
    if (j0 + i >= L) v[i] = -1e30f;
    mx = fmaxf(mx, v[i]);
  }
#pragma unroll
  for (int m = 1; m < 64; m <<= 1) mx = fmaxf(mx, __shfl_xor(mx, m));
  __shared__ float redM[4], redS[4];
  if ((threadIdx.x & 63) == 0) redM[threadIdx.x >> 6] = mx;
  __syncthreads();
  mx = fmaxf(fmaxf(redM[0], redM[1]), fmaxf(redM[2], redM[3]));
  float sum = 0.f;
#pragma unroll
  for (int i = 0; i < 8; ++i) {
    v[i] = (j0 + i < L) ? __expf(v[i] - mx) : 0.f;
    sum += v[i];
  }
#pragma unroll
  for (int m = 1; m < 64; m <<= 1) sum += __shfl_xor(sum, m);
  if ((threadIdx.x & 63) == 0) redS[threadIdx.x >> 6] = sum;
  __syncthreads();
  const float inv = 1.f / (redS[0] + redS[1] + redS[2] + redS[3]);
  ushort4 o1, o2;
  o1.x = f2bf(v[0] * inv); o1.y = f2bf(v[1] * inv);
  o1.z = f2bf(v[2] * inv); o1.w = f2bf(v[3] * inv);
  o2.x = f2bf(v[4] * inv); o2.y = f2bf(v[5] * inv);
  o2.z = f2bf(v[6] * inv); o2.w = f2bf(v[7] * inv);
  *(ushort4*)(dst + j0) = o1;
  *(ushort4*)(dst + j0 + 4) = o2;
}

// ---------------- 256^2 NT GEMM: pipelined, sync every 2 chunks --------------
// 8 waves (2Mx4N), wave tile 128x64 as 8m x 4n frags of 16x16.
// BK=32, 4-slot ring, swizzled LDS (verified 0-conflict), brick schedule.
// Pair (c even, c+1): even chunk has NO sync — its successor slot (c+1) was
// guaranteed landed FOR ALL WAVES by the previous rendezvous (each wave ran
// vmcnt before the barrier, so the barrier publishes everyone's loads).
// Odd chunk: vmcnt(4) + one barrier -> stages <= c+3 landed for next pair.
// Ledger: 1 stage (4 loads)/chunk; at rendezvous end of 2t+1, outstanding =
// last 3 stages; vmcnt(4) leaves newest 4 loads -> stages <= 2t+3 landed.
// Slot overwrite margin: overwriting stage issues >= 1 MFMA phase after the
// victim slot's last ds_read issue (reads done ~120cy; store lands >=400cy
// after issue).
// ng EVEN at every call site (64/32/128; PV limit is multiple of 8).
// EPI 0: bf16. 2: bf16 = Ep(bf16)*acc. 4: f32 raw at +z*zCout.
// CAUSAL 0: none. 1: skip 256-blocks with n0 > m0. 2: K-limit ng to (m0+256)/32.
template <int EPI, int CAUSAL>
__global__ __launch_bounds__(512, 2) void gemm256(
    const unsigned short* __restrict__ A, const unsigned short* __restrict__ Bw,
    void* __restrict__ Cp, const void* __restrict__ Ep,
    int N, int K, int nbx, int kLen, int ngTot,
    long long sAz, long long sBz, long long zCout) {
  __shared__ __align__(16) unsigned short lds[4 * 2 * 8192];  // 128KB
  __shared__ __align__(16) unsigned short ldsDummy[512];      // 1KB sink
  const int tid = threadIdx.x;
  const int wid = tid >> 6, l = tid & 63;
  const int wr = wid >> 2, wcn = wid & 3;

  // 2D-brick XCD schedule (4x8 block bricks per 32 consecutive lin ids)
  const int nwg = gridDim.x;
  const int q8 = nwg >> 3;
  const int lin = (blockIdx.x & 7) * q8 + (blockIdx.x >> 3);
  const int t32 = lin >> 5, r32 = lin & 31;
  const int tpr = nbx >> 3;
  const int tm = t32 / tpr, tn = t32 - tm * tpr;
  const long long m0 = (long long)(tm * 4 + (r32 >> 3)) * 256;
  const long long n0 = (long long)(tn * 8 + (r32 & 7)) * 256;
  if (CAUSAL == 1 && n0 > m0) return;
  const int z = blockIdx.z;
  A += z * sAz;
  Bw += z * sBz;
  const long long kbase = (long long)z * kLen;
  const long long zofs = (long long)z * zCout;
  int ng = ngTot;
  if (CAUSAL == 2) {
    const int lim = (int)((m0 + 256) >> 5);
    ng = lim < ng ? lim : ng;
  }

  // staging: both matrices of one chunk (4 loads/thread)
  const int stRow = (l >> 2);
  const int stCol = (((l & 3) ^ ((l >> 3) & 3))) * 8;  // pre-swizzled source col
  auto stage = [&](int chunk) {
    if (chunk < ng) {
      char* base = (char*)lds + ((chunk & 3) * 2) * 16384;
      const long long kcol = kbase + (long long)chunk * 32 + stCol;
#pragma unroll
      for (int i = 0; i < 2; ++i) {
        const int row = (wid * 2 + i) * 16 + stRow;
        gload_lds16(&A[(m0 + row) * K + kcol], base + (wid * 2 + i) * 1024);
        gload_lds16(&Bw[(n0 + row) * K + kcol],
                    base + 16384 + (wid * 2 + i) * 1024);
      }
    } else {
#pragma unroll
      for (int i = 0; i < 4; ++i) gload_lds16(&A[m0 * K], (char*)ldsDummy);
    }
  };

  // 16x16 frag read: row = base + (l&15), window = (l>>4) ^ ((row>>1)&3)
  const int ar = l & 15;
  const int rj = ((l >> 4) ^ ((l >> 1) & 3)) << 4;

  auto readA03 = [&](int slot, short8 (&a)[4]) {
    const char* sA = (const char*)lds + (slot * 2) * 16384;
#pragma unroll
    for (int m = 0; m < 4; ++m)
      a[m] = *(const short8*)(sA + (wr * 128 + m * 16 + ar) * 64 + rj);
  };
  auto readA47 = [&](int slot, short8 (&a)[4]) {
    const char* sA = (const char*)lds + (slot * 2) * 16384;
#pragma unroll
    for (int m = 0; m < 4; ++m)
      a[m] = *(const short8*)(sA + (wr * 128 + (m + 4) * 16 + ar) * 64 + rj);
  };
  auto readB = [&](int slot, short8 (&b)[4]) {
    const char* sB = (const char*)lds + (slot * 2 + 1) * 16384;
#pragma unroll
    for (int n = 0; n < 4; ++n)
      b[n] = *(const short8*)(sB + (wcn * 64 + n * 16 + ar) * 64 + rj);
  };

  f32x4 acc[8][4] = {};
  short8 aX[4], bX[4], aY[4], bY[4], a47[4];

  stage(0); stage(1); stage(2);
  asm volatile("s_waitcnt vmcnt(4)" ::: "memory");  // chunks 0,1 landed
  __builtin_amdgcn_s_barrier();
  readA03(0, aX);
  readB(0, bX);

  // SYNC=false: even chunk (no rendezvous; next chunk already published).
  // SYNC=true: odd chunk (vmcnt(4)+barrier before reading next pair's first).
  auto chunkBody = [&](int c, bool sync, short8 (&cur03)[4], short8 (&curB)[4],
                       short8 (&nxt03)[4], short8 (&nxtB)[4]) {
    const int slot = c & 3;
    // ---- phase 0 ----
    readA47(slot, a47);
    stage(c + 3);
    __builtin_amdgcn_s_setprio(1);
#pragma unroll
    for (int m = 0; m < 4; ++m)
#pragma unroll
      for (int n = 0; n < 4; ++n)
        acc[m][n] = mfma16(cur03[m], curB[n], acc[m][n]);
    __builtin_amdgcn_s_setprio(0);
    // ---- phase 1 ----
    if (sync) {
      asm volatile("s_waitcnt vmcnt(4)" ::: "memory");  // chunks c+1,c+2 landed
      __builtin_amdgcn_s_barrier();
    }
    readA03((c + 1) & 3, nxt03);
    readB((c + 1) & 3, nxtB);
    __builtin_amdgcn_s_setprio(1);
#pragma unroll
    for (int m = 0; m < 4; ++m)
#pragma unroll
      for (int n = 0; n < 4; ++n)
        acc[m + 4][n] = mfma16(a47[m], curB[n], acc[m + 4][n]);
    __builtin_amdgcn_s_setprio(0);
  };

  for (int c = 0; c < ng; c += 2) {
    chunkBody(c, false, aX, bX, aY, bY);
    chunkBody(c + 1, true, aY, bY, aX, bX);
  }
  asm volatile("s_waitcnt vmcnt(0)" ::: "memory");
  __builtin_amdgcn_s_barrier();

  const int orow = (l >> 4) * 4, ocol = l & 15;
#pragma unroll
  for (int m = 0; m < 8; ++m)
#pragma unroll
    for (int n = 0; n < 4; ++n)
#pragma unroll
      for (int r = 0; r < 4; ++r) {
        const long long gr = m0 + wr * 128 + m * 16 + orow + r;
        const long long gc = n0 + wcn * 64 + n * 16 + ocol;
        const long long idx = zofs + gr * N + gc;
        const float v = acc[m][n][r];
        if (EPI == 0) {
          ((unsigned short*)Cp)[idx] = f2bf(v);
        } else if (EPI == 2) {
          ((unsigned short*)Cp)[idx] = f2bf(bf2f(((const unsigned short*)Ep)[idx]) * v);
        } else {
          ((float*)Cp)[idx] = v;
        }
      }
}

// ---------------- split-K combine ----------------
__global__ __launch_bounds__(256) void combine2(
    const float* __restrict__ ep, const float* __restrict__ p,
    float* __restrict__ out, long long n4) {
  const float4* e4 = (const float4*)ep;
  const float4* p4 = (const float4*)p;
  float4* o4 = (float4*)out;
  for (long long i = blockIdx.x * 256 + threadIdx.x; i < n4; i += 2048 * 256) {
    float4 a = e4[i], b = p4[i], c = p4[i + n4];
    float4 o;
    o.x = a.x + b.x + c.x; o.y = a.y + b.y + c.y;
    o.z = a.z + b.z + c.z; o.w = a.w + b.w + c.w;
    o4[i] = o;
  }
}

extern "C" void kernel_launch(void* const* d_in, const int* in_sizes, int n_in,
                              void* d_out, int out_size, void* d_ws, size_t ws_size,
                              hipStream_t stream) {
  (void)in_sizes; (void)n_in; (void)out_size; (void)ws_size;
  const float* hidden = (const float*)d_in[0];
  const float* cosT = (const float*)d_in[2];
  const float* sinT = (const float*)d_in[3];
  const float* wq = (const float*)d_in[4];
  const float* wk = (const float*)d_in[5];
  const float* wv = (const float*)d_in[6];
  const float* wo = (const float*)d_in[7];
  const float* wg = (const float*)d_in[8];
  const float* wu = (const float*)d_in[9];
  const float* wd = (const float*)d_in[10];
  const float* ln1 = (const float*)d_in[11];
  const float* ln2 = (const float*)d_in[12];

  const size_t MB = 1ull << 20;
  char* ws = (char*)d_ws;
  unsigned short* xn    = (unsigned short*)(ws + 0);        // 16MB
  unsigned short* wqkvq = (unsigned short*)(ws + 16 * MB);  // 24MB
  unsigned short* qkv   = (unsigned short*)(ws + 40 * MB);  // 48MB
  unsigned short* qrb   = (unsigned short*)(ws + 88 * MB);  // 16MB
  unsigned short* krb   = (unsigned short*)(ws + 104 * MB); // 16MB
  unsigned short* vtb   = (unsigned short*)(ws + 120 * MB); // 16MB
  float*          scoresB = (float*)(ws + 0);               // 32MB alias
  unsigned short* probsB  = (unsigned short*)(ws + 40 * MB);// 16MB alias
  float*          part   = (float*)(ws + 0);                // 64MB alias
  unsigned short* wgq   = (unsigned short*)(ws + 0);        // 32MB alias
  unsigned short* wuq   = (unsigned short*)(ws + 32 * MB);  // 32MB alias
  unsigned short* gbuf  = (unsigned short*)(ws + 64 * MB);  // 64MB alias
  unsigned short* attnb = (unsigned short*)(ws + 136 * MB); // 16MB
  unsigned short* woq   = (unsigned short*)(ws + 152 * MB); // 8MB
  float*          hbuf  = (float*)(ws + 160 * MB);          // 32MB
  unsigned short* ybuf  = (unsigned short*)(ws + 192 * MB); // 16MB
  unsigned short* gated = (unsigned short*)(ws + 208 * MB); // 64MB
  unsigned short* wdq   = (unsigned short*)(ws + 272 * MB); // 32MB
  float* wspart         = (float*)(ws + 304 * MB);          // 28KB
  float* scales         = (float*)(ws + 304 * MB + 32768);

  // --- scales ---
  MArgs am;
  am.src[0] = wq; am.src[1] = wk; am.src[2] = wv; am.src[3] = wo;
  am.src[4] = wg; am.src[5] = wu; am.src[6] = wd;
  am.n[0] = am.n[1] = am.n[2] = am.n[3] = 4194304;
  am.n[4] = am.n[5] = am.n[6] = 16777216;
  for (int i = 0; i < 7; ++i) { am.dst[i] = nullptr; am.sidx[i] = i; }
  absmean_partial_multi<<<dim3(1024, 7), 256, 0, stream>>>(am, wspart);
  absmean_final<<<7, 256, 0, stream>>>(wspart, scales);

  // --- early quantize: wq,wk,wv,wo,wd ---
  MArgs qe;
  qe.src[0] = wq; qe.dst[0] = wqkvq;            qe.n[0] = 4194304;  qe.sidx[0] = 0;
  qe.src[1] = wk; qe.dst[1] = wqkvq + 4194304;  qe.n[1] = 4194304;  qe.sidx[1] = 1;
  qe.src[2] = wv; qe.dst[2] = wqkvq + 8388608;  qe.n[2] = 4194304;  qe.sidx[2] = 2;
  qe.src[3] = wo; qe.dst[3] = woq;              qe.n[3] = 4194304;  qe.sidx[3] = 3;
  qe.src[4] = wd; qe.dst[4] = wdq;              qe.n[4] = 16777216; qe.sidx[4] = 6;
  qe.src[5] = wq; qe.dst[5] = nullptr; qe.n[5] = 0; qe.sidx[5] = 0;
  qe.src[6] = wq; qe.dst[6] = nullptr; qe.n[6] = 0; qe.sidx[6] = 0;
  quantize_multi<<<dim3(2048, 5), 256, 0, stream>>>(qe, scales);

  rmsnorm_k<<<4096, 256, 0, stream>>>(hidden, ln1, xn);

  // QKV: [4096x6144x2048], grid 384, 64 K-chunks
  gemm256<0, 0><<<dim3(384, 1, 1), 512, 0, stream>>>(
      xn, wqkvq, qkv, nullptr, 6144, 2048, 24, 2048, 64, 0, 0, 0);

  rope_k<<<16384, 256, 0, stream>>>(qkv, cosT, sinT, qrb, krb, vtb);

  // attention (full-D per batch): QK causal block-skip, PV K-limited
  gemm256<4, 1><<<dim3(64, 1, 2), 512, 0, stream>>>(
      qrb, krb, scoresB, nullptr, 2048, 2048, 8, 0, 64, 4194304, 4194304, 4194304);
  softmax_causal<<<4096, 256, 0, stream>>>(scoresB, probsB);
  gemm256<0, 2><<<dim3(64, 1, 2), 512, 0, stream>>>(
      probsB, vtb, attnb, nullptr, 2048, 2048, 8, 0, 64, 4194304, 4194304, 4194304);

  // O-proj: split-K=2 -> combine with residual
  gemm256<4, 0><<<dim3(128, 1, 2), 512, 0, stream>>>(
      attnb, woq, part, nullptr, 2048, 2048, 8, 1024, 32, 0, 0, 8388608);
  combine2<<<2048, 256, 0, stream>>>(hidden, part, hbuf, 2097152);

  // late quantize: wg, wu
  MArgs ql;
  ql.src[0] = wg; ql.dst[0] = wgq; ql.n[0] = 16777216; ql.sidx[0] = 4;
  ql.src[1] = wu; ql.dst[1] = wuq; ql.n[1] = 16777216; ql.sidx[1] = 5;
  for (int i = 2; i < 7; ++i) { ql.src[i] = wg; ql.dst[i] = nullptr; ql.n[i] = 0; ql.sidx[i] = 0; }
  quantize_multi<<<dim3(2048, 2), 256, 0, stream>>>(ql, scales);

  rmsnorm_k<<<4096, 256, 0, stream>>>(hbuf, ln2, ybuf);

  // G, U: [4096x8192x2048], grid 512, 64 K-chunks
  gemm256<0, 0><<<dim3(512, 1, 1), 512, 0, stream>>>(
      ybuf, wgq, gbuf, nullptr, 8192, 2048, 32, 2048, 64, 0, 0, 0);
  gemm256<2, 0><<<dim3(512, 1, 1), 512, 0, stream>>>(
      ybuf, wuq, gated, gbuf, 8192, 2048, 32, 2048, 64, 0, 0, 0);

  // D: [4096x2048x8192] split-K=2 -> combine into d_out
  gemm256<4, 0><<<dim3(128, 1, 2), 512, 0, stream>>>(
      gated, wdq, part, nullptr, 2048, 8192, 8, 4096, 128, 0, 0, 8388608);
  combine2<<<2048, 256, 0, stream>>>(hbuf, part, (float*)d_out, 2097152);
}

// Round 10
// 818.811 us; speedup vs baseline: 1.1999x; 1.0073x over previous
//
#include <hip/hip_runtime.h>
#include <stdint.h>

#define DEV __device__ __forceinline__

typedef __attribute__((ext_vector_type(8))) short short8;
typedef __attribute__((ext_vector_type(8))) __bf16 bf16x8;
typedef __attribute__((ext_vector_type(4))) float f32x4;

DEV unsigned short f2bf(float f) {
  union { float f; unsigned int u; } v; v.f = f;
  unsigned int r = v.u + 0x7fffu + ((v.u >> 16) & 1u);
  return (unsigned short)(r >> 16);
}
DEV float bf2f(unsigned short h) {
  union { unsigned int u; float f; } v; v.u = ((unsigned int)h) << 16;
  return v.f;
}
DEV f32x4 mfma16(short8 a, short8 b, f32x4 c) {
  return __builtin_amdgcn_mfma_f32_16x16x32_bf16(
      __builtin_bit_cast(bf16x8, a), __builtin_bit_cast(bf16x8, b), c, 0, 0, 0);
}
DEV void gload_lds16(const void* g, void* lds) {
  __builtin_amdgcn_global_load_lds(
      (const __attribute__((address_space(1))) void*)g,
      (__attribute__((address_space(3))) void*)lds, 16, 0, 0);
}

struct MArgs {
  const float* src[7];
  unsigned short* dst[7];
  int n[7];
  int sidx[7];
};

// ---------------- abs-mean partial (all matrices, one launch) ----------------
__global__ __launch_bounds__(256) void absmean_partial_multi(
    MArgs a, float* __restrict__ partial) {
  const int m = blockIdx.y;
  const float4* w4 = (const float4*)a.src[m];
  const int n4 = a.n[m] >> 2;
  float s = 0.f;
  for (int i = blockIdx.x * 256 + threadIdx.x; i < n4; i += 1024 * 256) {
    float4 v = w4[i];
    s += fabsf(v.x) + fabsf(v.y) + fabsf(v.z) + fabsf(v.w);
  }
#pragma unroll
  for (int mm = 1; mm < 64; mm <<= 1) s += __shfl_xor(s, mm);
  __shared__ float red[4];
  if ((threadIdx.x & 63) == 0) red[threadIdx.x >> 6] = s;
  __syncthreads();
  if (threadIdx.x == 0)
    partial[m * 1024 + blockIdx.x] = red[0] + red[1] + red[2] + red[3];
}

__global__ __launch_bounds__(256) void absmean_final(
    const float* __restrict__ partial, float* __restrict__ scales) {
  __shared__ double red[256];
  const int m = blockIdx.x;
  double s = 0.0;
  for (int i = threadIdx.x; i < 1024; i += 256) s += (double)partial[m * 1024 + i];
  red[threadIdx.x] = s;
  __syncthreads();
  for (int t = 128; t > 0; t >>= 1) {
    if (threadIdx.x < t) red[threadIdx.x] += red[threadIdx.x + t];
    __syncthreads();
  }
  if (threadIdx.x == 0) {
    const long long cnt = (m < 4) ? 4194304ll : 16777216ll;
    scales[m] = (float)(red[0] / (double)cnt);
  }
}

// ---------------- ternary quantize -> bf16 (batched) ----------------
__global__ __launch_bounds__(256) void quantize_multi(
    MArgs a, const float* __restrict__ scales) {
  const int m = blockIdx.y;
  const float sc = scales[a.sidx[m]];
  const float inv = 1.f / (sc + 1e-5f);
  const float4* src = (const float4*)a.src[m];
  ushort4* dst = (ushort4*)a.dst[m];
  const int n4 = a.n[m] >> 2;
  for (int i = blockIdx.x * 256 + threadIdx.x; i < n4; i += 2048 * 256) {
    float4 v = src[i];
    ushort4 o;
    o.x = f2bf(fminf(fmaxf(rintf(v.x * inv), -1.f), 1.f) * sc);
    o.y = f2bf(fminf(fmaxf(rintf(v.y * inv), -1.f), 1.f) * sc);
    o.z = f2bf(fminf(fmaxf(rintf(v.z * inv), -1.f), 1.f) * sc);
    o.w = f2bf(fminf(fmaxf(rintf(v.w * inv), -1.f), 1.f) * sc);
    dst[i] = o;
  }
}

// ---------------- RMSNorm (f32 in -> bf16 out) ----------------
__global__ __launch_bounds__(256) void rmsnorm_k(
    const float* __restrict__ x, const float* __restrict__ wt,
    unsigned short* __restrict__ out) {
  const long long t = blockIdx.x;
  const float* xr = x + t * 2048;
  const int i0 = threadIdx.x * 8;
  float4 a = *(const float4*)(xr + i0);
  float4 b = *(const float4*)(xr + i0 + 4);
  float ss = a.x * a.x + a.y * a.y + a.z * a.z + a.w * a.w +
             b.x * b.x + b.y * b.y + b.z * b.z + b.w * b.w;
#pragma unroll
  for (int m = 1; m < 64; m <<= 1) ss += __shfl_xor(ss, m);
  __shared__ float red[4];
  if ((threadIdx.x & 63) == 0) red[threadIdx.x >> 6] = ss;
  __syncthreads();
  float tot = red[0] + red[1] + red[2] + red[3];
  float rs = rsqrtf(tot * (1.f / 2048.f) + 1e-5f);
  float4 wa = *(const float4*)(wt + i0);
  float4 wb = *(const float4*)(wt + i0 + 4);
  ushort4 o1, o2;
  o1.x = f2bf(a.x * wa.x * rs); o1.y = f2bf(a.y * wa.y * rs);
  o1.z = f2bf(a.z * wa.z * rs); o1.w = f2bf(a.w * wa.w * rs);
  o2.x = f2bf(b.x * wb.x * rs); o2.y = f2bf(b.y * wb.y * rs);
  o2.z = f2bf(b.z * wb.z * rs); o2.w = f2bf(b.w * wb.w * rs);
  *(ushort4*)(out + t * 2048 + i0) = o1;
  *(ushort4*)(out + t * 2048 + i0 + 4) = o2;
}

// -------- fused O-combine + RMSNorm(ln2): h = ep+p0+p1; y = rms(h)*w --------
__global__ __launch_bounds__(256) void combine_rms(
    const float* __restrict__ ep, const float* __restrict__ p,
    const float* __restrict__ wt, float* __restrict__ hout,
    unsigned short* __restrict__ yout) {
  const long long t = blockIdx.x;
  const int i0 = threadIdx.x * 8;
  const long long base = t * 2048 + i0;
  float4 e1 = *(const float4*)(ep + base);
  float4 e2 = *(const float4*)(ep + base + 4);
  float4 p1 = *(const float4*)(p + base);
  float4 p2 = *(const float4*)(p + base + 4);
  float4 q1 = *(const float4*)(p + 8388608 + base);
  float4 q2 = *(const float4*)(p + 8388608 + base + 4);
  float h[8] = {e1.x + p1.x + q1.x, e1.y + p1.y + q1.y,
                e1.z + p1.z + q1.z, e1.w + p1.w + q1.w,
                e2.x + p2.x + q2.x, e2.y + p2.y + q2.y,
                e2.z + p2.z + q2.z, e2.w + p2.w + q2.w};
  float4 h1 = {h[0], h[1], h[2], h[3]};
  float4 h2 = {h[4], h[5], h[6], h[7]};
  *(float4*)(hout + base) = h1;
  *(float4*)(hout + base + 4) = h2;
  float ss = 0.f;
#pragma unroll
  for (int i = 0; i < 8; ++i) ss += h[i] * h[i];
#pragma unroll
  for (int m = 1; m < 64; m <<= 1) ss += __shfl_xor(ss, m);
  __shared__ float red[4];
  if ((threadIdx.x & 63) == 0) red[threadIdx.x >> 6] = ss;
  __syncthreads();
  const float tot = red[0] + red[1] + red[2] + red[3];
  const float rs = rsqrtf(tot * (1.f / 2048.f) + 1e-5f);
  float4 wa = *(const float4*)(wt + i0);
  float4 wb = *(const float4*)(wt + i0 + 4);
  ushort4 o1, o2;
  o1.x = f2bf(h[0] * wa.x * rs); o1.y = f2bf(h[1] * wa.y * rs);
  o1.z = f2bf(h[2] * wa.z * rs); o1.w = f2bf(h[3] * wa.w * rs);
  o2.x = f2bf(h[4] * wb.x * rs); o2.y = f2bf(h[5] * wb.y * rs);
  o2.z = f2bf(h[6] * wb.z * rs); o2.w = f2bf(h[7] * wb.w * rs);
  *(ushort4*)(yout + base) = o1;
  *(ushort4*)(yout + base + 4) = o2;
}

// ---------------- RoPE + V transpose ----------------
__global__ __launch_bounds__(256) void rope_k(
    const unsigned short* __restrict__ qkv, const float* __restrict__ cosT,
    const float* __restrict__ sinT, unsigned short* __restrict__ qr,
    unsigned short* __restrict__ kr, unsigned short* __restrict__ vt) {
  const long long gid = (long long)blockIdx.x * 256 + threadIdx.x;
  const int t = (int)(gid >> 10);
  const int r = (int)(gid & 1023);
  const int h = r >> 6, d = r & 63;
  const int s = t & 2047, b = t >> 11;
  const unsigned short* row = qkv + (long long)t * 6144;
  const float c = cosT[s * 128 + d], sn = sinT[s * 128 + d];
  const int col = h * 128 + d;
  const float SC = 0.08838834764831845f;  // 1/sqrt(128)
  float q1 = bf2f(row[col]), q2 = bf2f(row[col + 64]);
  float k1 = bf2f(row[2048 + col]), k2 = bf2f(row[2048 + col + 64]);
  long long ob = (long long)t * 2048 + col;
  qr[ob] = f2bf((q1 * c - q2 * sn) * SC);
  qr[ob + 64] = f2bf((q2 * c + q1 * sn) * SC);
  kr[ob] = f2bf(k1 * c - k2 * sn);
  kr[ob + 64] = f2bf(k2 * c + k1 * sn);
  vt[((long long)b * 2048 + col) * 2048 + s] = row[4096 + col];
  vt[((long long)b * 2048 + col + 64) * 2048 + s] = row[4096 + col + 64];
}

// ---------------- causal row softmax (single global read, regs) ----------------
__global__ __launch_bounds__(256) void softmax_causal(
    const float* __restrict__ scores, unsigned short* __restrict__ probs) {
  const int r = blockIdx.x;
  const int s = r & 2047;
  const float* src = scores + (long long)r * 2048;
  unsigned short* dst = probs + (long long)r * 2048;
  const int L = s + 1;
  const int j0 = threadIdx.x * 8;
  float4 a = *(const float4*)(src + j0);
  float4 b = *(const float4*)(src + j0 + 4);
  float v[8] = {a.x, a.y, a.z, a.w, b.x, b.y, b.z, b.w};
  float mx = -1e30f;
#pragma unroll
  for (int i = 0; i < 8; ++i) {
    if (j0 + i >= L) v[i] = -1e30f;
    mx = fmaxf(mx, v[i]);
  }
#pragma unroll
  for (int m = 1; m < 64; m <<= 1) mx = fmaxf(mx, __shfl_xor(mx, m));
  __shared__ float redM[4], redS[4];
  if ((threadIdx.x & 63) == 0) redM[threadIdx.x >> 6] = mx;
  __syncthreads();
  mx = fmaxf(fmaxf(redM[0], redM[1]), fmaxf(redM[2], redM[3]));
  float sum = 0.f;
#pragma unroll
  for (int i = 0; i < 8; ++i) {
    v[i] = (j0 + i < L) ? __expf(v[i] - mx) : 0.f;
    sum += v[i];
  }
#pragma unroll
  for (int m = 1; m < 64; m <<= 1) sum += __shfl_xor(sum, m);
  if ((threadIdx.x & 63) == 0) redS[threadIdx.x >> 6] = sum;
  __syncthreads();
  const float inv = 1.f / (redS[0] + redS[1] + redS[2] + redS[3]);
  ushort4 o1, o2;
  o1.x = f2bf(v[0] * inv); o1.y = f2bf(v[1] * inv);
  o1.z = f2bf(v[2] * inv); o1.w = f2bf(v[3] * inv);
  o2.x = f2bf(v[4] * inv); o2.y = f2bf(v[5] * inv);
  o2.z = f2bf(v[6] * inv); o2.w = f2bf(v[7] * inv);
  *(ushort4*)(dst + j0) = o1;
  *(ushort4*)(dst + j0 + 4) = o2;
}

// ---------------- 256^2 NT GEMM: pipelined, 4-unrolled (static slots) --------
// 8 waves (2Mx4N), wave tile 128x64 as 8m x 4n frags of 16x16.
// BK=32, 4-slot ring, swizzled LDS (0-conflict verified), brick schedule,
// reads one phase ahead, rendezvous (vmcnt(4)+barrier) every 2 chunks.
// 4-chunk unroll makes every LDS slot base a compile-time immediate.
// Ledger (stage(k) issued in chunk k-3): prev sync guarantees stages<=c+1;
// chunk c issues c+3; chunk c+1 issues c+4 then vmcnt(4) -> newest 4 (stage
// c+4) may remain -> stages<=c+3 landed, covering slots read by chunks
// c+1 (slot c+2) and c+2 (slot c+3). ng % 4 == 0 at every call site.
// EPI 0: bf16. 2: bf16 = Ep(bf16)*acc. 4: f32 raw at +z*zCout.
// CAUSAL 0: none. 1: skip 256-blocks with n0 > m0. 2: K-limit ng to (m0+256)/32.
template <int EPI, int CAUSAL>
__global__ __launch_bounds__(512, 2) void gemm256(
    const unsigned short* __restrict__ A, const unsigned short* __restrict__ Bw,
    void* __restrict__ Cp, const void* __restrict__ Ep,
    int N, int K, int nbx, int kLen, int ngTot,
    long long sAz, long long sBz, long long zCout) {
  __shared__ __align__(16) unsigned short lds[4 * 2 * 8192];  // 128KB
  __shared__ __align__(16) unsigned short ldsDummy[512];      // 1KB sink
  const int tid = threadIdx.x;
  const int wid = tid >> 6, l = tid & 63;
  const int wr = wid >> 2, wcn = wid & 3;

  // 2D-brick XCD schedule (4x8 block bricks per 32 consecutive lin ids)
  const int nwg = gridDim.x;
  const int q8 = nwg >> 3;
  const int lin = (blockIdx.x & 7) * q8 + (blockIdx.x >> 3);
  const int t32 = lin >> 5, r32 = lin & 31;
  const int tpr = nbx >> 3;
  const int tm = t32 / tpr, tn = t32 - tm * tpr;
  const long long m0 = (long long)(tm * 4 + (r32 >> 3)) * 256;
  const long long n0 = (long long)(tn * 8 + (r32 & 7)) * 256;
  if (CAUSAL == 1 && n0 > m0) return;
  const int z = blockIdx.z;
  A += z * sAz;
  Bw += z * sBz;
  const long long kbase = (long long)z * kLen;
  const long long zofs = (long long)z * zCout;
  int ng = ngTot;
  if (CAUSAL == 2) {
    const int lim = (int)((m0 + 256) >> 5);
    ng = lim < ng ? lim : ng;
  }

  // staging: both matrices of one chunk (4 loads/thread); sslot compile-time
  const int stRow = (l >> 2);
  const int stCol = (((l & 3) ^ ((l >> 3) & 3))) * 8;  // pre-swizzled source col
  auto stage = [&](int chunk, int sslot) {
    if (chunk < ng) {
      char* base = (char*)lds + (sslot * 2) * 16384;
      const long long kcol = kbase + (long long)chunk * 32 + stCol;
#pragma unroll
      for (int i = 0; i < 2; ++i) {
        const int row = (wid * 2 + i) * 16 + stRow;
        gload_lds16(&A[(m0 + row) * K + kcol], base + (wid * 2 + i) * 1024);
        gload_lds16(&Bw[(n0 + row) * K + kcol],
                    base + 16384 + (wid * 2 + i) * 1024);
      }
    } else {
#pragma unroll
      for (int i = 0; i < 4; ++i) gload_lds16(&A[m0 * K], (char*)ldsDummy);
    }
  };

  // 16x16 frag read: row = base + (l&15), window = (l>>4) ^ ((row>>1)&3)
  const int ar = l & 15;
  const int rj = ((l >> 4) ^ ((l >> 1) & 3)) << 4;
  const int aoff = (wr * 128 + ar) * 64 + rj;   // + m*1024 (+4096 for m+4)
  const int boff = (wcn * 64 + ar) * 64 + rj;   // + n*1024

  f32x4 acc[8][4] = {};
  short8 aX[4], bX[4], aY[4], bY[4];

  stage(0, 0); stage(1, 1); stage(2, 2);
  asm volatile("s_waitcnt vmcnt(4)" ::: "memory");  // chunks 0,1 landed
  __builtin_amdgcn_s_barrier();
#pragma unroll
  for (int m = 0; m < 4; ++m)
    aX[m] = *(const short8*)((const char*)lds + aoff + m * 1024);
#pragma unroll
  for (int n = 0; n < 4; ++n)
    bX[n] = *(const short8*)((const char*)lds + 16384 + boff + n * 1024);

// SLOT/NSLOT compile-time; SYNC on odd chunks (rendezvous every 2 chunks).
#define CHUNK_BODY(SLOT, NSLOT, SYNC, cur03, curB, nxt03, nxtB, cc)            \
  {                                                                            \
    const char* sAc = (const char*)lds + (SLOT * 2) * 16384;                   \
    const char* sAn = (const char*)lds + (NSLOT * 2) * 16384;                  \
    const char* sBn = (const char*)lds + (NSLOT * 2 + 1) * 16384;              \
    short8 a47[4];                                                             \
    _Pragma("unroll") for (int m = 0; m < 4; ++m)                              \
        a47[m] = *(const short8*)(sAc + aoff + 4096 + m * 1024);               \
    stage((cc) + 3, (SLOT + 3) & 3);                                           \
    __builtin_amdgcn_s_setprio(1);                                             \
    _Pragma("unroll") for (int m = 0; m < 4; ++m)                              \
      _Pragma("unroll") for (int n = 0; n < 4; ++n)                            \
          acc[m][n] = mfma16(cur03[m], curB[n], acc[m][n]);                    \
    __builtin_amdgcn_s_setprio(0);                                             \
    if (SYNC) {                                                                \
      asm volatile("s_waitcnt vmcnt(4)" ::: "memory");                         \
      __builtin_amdgcn_s_barrier();                                            \
    }                                                                          \
    _Pragma("unroll") for (int m = 0; m < 4; ++m)                              \
        nxt03[m] = *(const short8*)(sAn + aoff + m * 1024);                    \
    _Pragma("unroll") for (int n = 0; n < 4; ++n)                              \
        nxtB[n] = *(const short8*)(sBn + boff + n * 1024);                     \
    __builtin_amdgcn_s_setprio(1);                                             \
    _Pragma("unroll") for (int m = 0; m < 4; ++m)                              \
      _Pragma("unroll") for (int n = 0; n < 4; ++n)                            \
          acc[m + 4][n] = mfma16(a47[m], curB[n], acc[m + 4][n]);              \
    __builtin_amdgcn_s_setprio(0);                                             \
  }

  for (int c = 0; c < ng; c += 4) {
    CHUNK_BODY(0, 1, false, aX, bX, aY, bY, c);
    CHUNK_BODY(1, 2, true, aY, bY, aX, bX, c + 1);
    CHUNK_BODY(2, 3, false, aX, bX, aY, bY, c + 2);
    CHUNK_BODY(3, 0, true, aY, bY, aX, bX, c + 3);
  }
#undef CHUNK_BODY
  asm volatile("s_waitcnt vmcnt(0)" ::: "memory");
  __builtin_amdgcn_s_barrier();

  const int orow = (l >> 4) * 4, ocol = l & 15;
#pragma unroll
  for (int m = 0; m < 8; ++m)
#pragma unroll
    for (int n = 0; n < 4; ++n)
#pragma unroll
      for (int r = 0; r < 4; ++r) {
        const long long gr = m0 + wr * 128 + m * 16 + orow + r;
        const long long gc = n0 + wcn * 64 + n * 16 + ocol;
        const long long idx = zofs + gr * N + gc;
        const float v = acc[m][n][r];
        if (EPI == 0) {
          ((unsigned short*)Cp)[idx] = f2bf(v);
        } else if (EPI == 2) {
          ((unsigned short*)Cp)[idx] = f2bf(bf2f(((const unsigned short*)Ep)[idx]) * v);
        } else {
          ((float*)Cp)[idx] = v;
        }
      }
}

// ---------------- split-K combine (D path) ----------------
__global__ __launch_bounds__(256) void combine2(
    const float* __restrict__ ep, const float* __restrict__ p,
    float* __restrict__ out, long long n4) {
  const float4* e4 = (const float4*)ep;
  const float4* p4 = (const float4*)p;
  float4* o4 = (float4*)out;
  for (long long i = blockIdx.x * 256 + threadIdx.x; i < n4; i += 2048 * 256) {
    float4 a = e4[i], b = p4[i], c = p4[i + n4];
    float4 o;
    o.x = a.x + b.x + c.x; o.y = a.y + b.y + c.y;
    o.z = a.z + b.z + c.z; o.w = a.w + b.w + c.w;
    o4[i] = o;
  }
}

extern "C" void kernel_launch(void* const* d_in, const int* in_sizes, int n_in,
                              void* d_out, int out_size, void* d_ws, size_t ws_size,
                              hipStream_t stream) {
  (void)in_sizes; (void)n_in; (void)out_size; (void)ws_size;
  const float* hidden = (const float*)d_in[0];
  const float* cosT = (const float*)d_in[2];
  const float* sinT = (const float*)d_in[3];
  const float* wq = (const float*)d_in[4];
  const float* wk = (const float*)d_in[5];
  const float* wv = (const float*)d_in[6];
  const float* wo = (const float*)d_in[7];
  const float* wg = (const float*)d_in[8];
  const float* wu = (const float*)d_in[9];
  const float* wd = (const float*)d_in[10];
  const float* ln1 = (const float*)d_in[11];
  const float* ln2 = (const float*)d_in[12];

  const size_t MB = 1ull << 20;
  char* ws = (char*)d_ws;
  unsigned short* xn    = (unsigned short*)(ws + 0);        // 16MB
  unsigned short* wqkvq = (unsigned short*)(ws + 16 * MB);  // 24MB
  unsigned short* qkv   = (unsigned short*)(ws + 40 * MB);  // 48MB
  unsigned short* qrb   = (unsigned short*)(ws + 88 * MB);  // 16MB
  unsigned short* krb   = (unsigned short*)(ws + 104 * MB); // 16MB
  unsigned short* vtb   = (unsigned short*)(ws + 120 * MB); // 16MB
  float*          scoresB = (float*)(ws + 0);               // 32MB alias
  unsigned short* probsB  = (unsigned short*)(ws + 40 * MB);// 16MB alias
  float*          part   = (float*)(ws + 0);                // 64MB alias
  unsigned short* wgq   = (unsigned short*)(ws + 0);        // 32MB alias
  unsigned short* wuq   = (unsigned short*)(ws + 32 * MB);  // 32MB alias
  unsigned short* gbuf  = (unsigned short*)(ws + 64 * MB);  // 64MB alias
  unsigned short* attnb = (unsigned short*)(ws + 136 * MB); // 16MB
  unsigned short* woq   = (unsigned short*)(ws + 152 * MB); // 8MB
  float*          hbuf  = (float*)(ws + 160 * MB);          // 32MB
  unsigned short* ybuf  = (unsigned short*)(ws + 192 * MB); // 16MB
  unsigned short* gated = (unsigned short*)(ws + 208 * MB); // 64MB
  unsigned short* wdq   = (unsigned short*)(ws + 272 * MB); // 32MB
  float* wspart         = (float*)(ws + 304 * MB);          // 28KB
  float* scales         = (float*)(ws + 304 * MB + 32768);

  // --- scales ---
  MArgs am;
  am.src[0] = wq; am.src[1] = wk; am.src[2] = wv; am.src[3] = wo;
  am.src[4] = wg; am.src[5] = wu; am.src[6] = wd;
  am.n[0] = am.n[1] = am.n[2] = am.n[3] = 4194304;
  am.n[4] = am.n[5] = am.n[6] = 16777216;
  for (int i = 0; i < 7; ++i) { am.dst[i] = nullptr; am.sidx[i] = i; }
  absmean_partial_multi<<<dim3(1024, 7), 256, 0, stream>>>(am, wspart);
  absmean_final<<<7, 256, 0, stream>>>(wspart, scales);

  // --- early quantize: wq,wk,wv,wo,wd ---
  MArgs qe;
  qe.src[0] = wq; qe.dst[0] = wqkvq;            qe.n[0] = 4194304;  qe.sidx[0] = 0;
  qe.src[1] = wk; qe.dst[1] = wqkvq + 4194304;  qe.n[1] = 4194304;  qe.sidx[1] = 1;
  qe.src[2] = wv; qe.dst[2] = wqkvq + 8388608;  qe.n[2] = 4194304;  qe.sidx[2] = 2;
  qe.src[3] = wo; qe.dst[3] = woq;              qe.n[3] = 4194304;  qe.sidx[3] = 3;
  qe.src[4] = wd; qe.dst[4] = wdq;              qe.n[4] = 16777216; qe.sidx[4] = 6;
  qe.src[5] = wq; qe.dst[5] = nullptr; qe.n[5] = 0; qe.sidx[5] = 0;
  qe.src[6] = wq; qe.dst[6] = nullptr; qe.n[6] = 0; qe.sidx[6] = 0;
  quantize_multi<<<dim3(2048, 5), 256, 0, stream>>>(qe, scales);

  rmsnorm_k<<<4096, 256, 0, stream>>>(hidden, ln1, xn);

  // QKV: [4096x6144x2048], grid 384, 64 K-chunks
  gemm256<0, 0><<<dim3(384, 1, 1), 512, 0, stream>>>(
      xn, wqkvq, qkv, nullptr, 6144, 2048, 24, 2048, 64, 0, 0, 0);

  rope_k<<<16384, 256, 0, stream>>>(qkv, cosT, sinT, qrb, krb, vtb);

  // attention (full-D per batch): QK causal block-skip, PV K-limited
  gemm256<4, 1><<<dim3(64, 1, 2), 512, 0, stream>>>(
      qrb, krb, scoresB, nullptr, 2048, 2048, 8, 0, 64, 4194304, 4194304, 4194304);
  softmax_causal<<<4096, 256, 0, stream>>>(scoresB, probsB);
  gemm256<0, 2><<<dim3(64, 1, 2), 512, 0, stream>>>(
      probsB, vtb, attnb, nullptr, 2048, 2048, 8, 0, 64, 4194304, 4194304, 4194304);

  // O-proj: split-K=2 -> fused combine + ln2 RMSNorm
  gemm256<4, 0><<<dim3(128, 1, 2), 512, 0, stream>>>(
      attnb, woq, part, nullptr, 2048, 2048, 8, 1024, 32, 0, 0, 8388608);
  combine_rms<<<4096, 256, 0, stream>>>(hidden, part, ln2, hbuf, ybuf);

  // late quantize: wg, wu
  MArgs ql;
  ql.src[0] = wg; ql.dst[0] = wgq; ql.n[0] = 16777216; ql.sidx[0] = 4;
  ql.src[1] = wu; ql.dst[1] = wuq; ql.n[1] = 16777216; ql.sidx[1] = 5;
  for (int i = 2; i < 7; ++i) { ql.src[i] = wg; ql.dst[i] = nullptr; ql.n[i] = 0; ql.sidx[i] = 0; }
  quantize_multi<<<dim3(2048, 2), 256, 0, stream>>>(ql, scales);

  // G, U: [4096x8192x2048], grid 512, 64 K-chunks
  gemm256<0, 0><<<dim3(512, 1, 1), 512, 0, stream>>>(
      ybuf, wgq, gbuf, nullptr, 8192, 2048, 32, 2048, 64, 0, 0, 0);
  gemm256<2, 0><<<dim3(512, 1, 1), 512, 0, stream>>>(
      ybuf, wuq, gated, gbuf, 8192, 2048, 32, 2048, 64, 0, 0, 0);

  // D: [4096x2048x8192] split-K=2 -> combine into d_out
  gemm256<4, 0><<<dim3(128, 1, 2), 512, 0, stream>>>(
      gated, wdq, part, nullptr, 2048, 8192, 8, 4096, 128, 0, 0, 8388608);
  combine2<<<2048, 256, 0, stream>>>(hbuf, part, (float*)d_out, 2097152);
}

// Round 11
// 772.521 us; speedup vs baseline: 1.2718x; 1.0599x over previous
//
#include <hip/hip_runtime.h>
#include <stdint.h>

#define DEV __device__ __forceinline__

typedef __attribute__((ext_vector_type(8))) short short8;
typedef __attribute__((ext_vector_type(8))) __bf16 bf16x8;
typedef __attribute__((ext_vector_type(4))) float f32x4;

DEV unsigned short f2bf(float f) {
  union { float f; unsigned int u; } v; v.f = f;
  unsigned int r = v.u + 0x7fffu + ((v.u >> 16) & 1u);
  return (unsigned short)(r >> 16);
}
DEV float bf2f(unsigned short h) {
  union { unsigned int u; float f; } v; v.u = ((unsigned int)h) << 16;
  return v.f;
}
DEV f32x4 mfma16(short8 a, short8 b, f32x4 c) {
  return __builtin_amdgcn_mfma_f32_16x16x32_bf16(
      __builtin_bit_cast(bf16x8, a), __builtin_bit_cast(bf16x8, b), c, 0, 0, 0);
}
DEV void gload_lds16(const void* g, void* lds) {
  __builtin_amdgcn_global_load_lds(
      (const __attribute__((address_space(1))) void*)g,
      (__attribute__((address_space(3))) void*)lds, 16, 0, 0);
}

struct MArgs {
  const float* src[7];
  unsigned short* dst[7];
  int n[7];
  int sidx[7];
};

// ---------------- abs-mean partial (all matrices, one launch) ----------------
__global__ __launch_bounds__(256) void absmean_partial_multi(
    MArgs a, float* __restrict__ partial) {
  const int m = blockIdx.y;
  const float4* w4 = (const float4*)a.src[m];
  const int n4 = a.n[m] >> 2;
  float s = 0.f;
  for (int i = blockIdx.x * 256 + threadIdx.x; i < n4; i += 1024 * 256) {
    float4 v = w4[i];
    s += fabsf(v.x) + fabsf(v.y) + fabsf(v.z) + fabsf(v.w);
  }
#pragma unroll
  for (int mm = 1; mm < 64; mm <<= 1) s += __shfl_xor(s, mm);
  __shared__ float red[4];
  if ((threadIdx.x & 63) == 0) red[threadIdx.x >> 6] = s;
  __syncthreads();
  if (threadIdx.x == 0)
    partial[m * 1024 + blockIdx.x] = red[0] + red[1] + red[2] + red[3];
}

__global__ __launch_bounds__(256) void absmean_final(
    const float* __restrict__ partial, float* __restrict__ scales) {
  __shared__ double red[256];
  const int m = blockIdx.x;
  double s = 0.0;
  for (int i = threadIdx.x; i < 1024; i += 256) s += (double)partial[m * 1024 + i];
  red[threadIdx.x] = s;
  __syncthreads();
  for (int t = 128; t > 0; t >>= 1) {
    if (threadIdx.x < t) red[threadIdx.x] += red[threadIdx.x + t];
    __syncthreads();
  }
  if (threadIdx.x == 0) {
    const long long cnt = (m < 4) ? 4194304ll : 16777216ll;
    scales[m] = (float)(red[0] / (double)cnt);
  }
}

// ---------------- ternary quantize -> bf16 (batched) ----------------
__global__ __launch_bounds__(256) void quantize_multi(
    MArgs a, const float* __restrict__ scales) {
  const int m = blockIdx.y;
  const float sc = scales[a.sidx[m]];
  const float inv = 1.f / (sc + 1e-5f);
  const float4* src = (const float4*)a.src[m];
  ushort4* dst = (ushort4*)a.dst[m];
  const int n4 = a.n[m] >> 2;
  for (int i = blockIdx.x * 256 + threadIdx.x; i < n4; i += 2048 * 256) {
    float4 v = src[i];
    ushort4 o;
    o.x = f2bf(fminf(fmaxf(rintf(v.x * inv), -1.f), 1.f) * sc);
    o.y = f2bf(fminf(fmaxf(rintf(v.y * inv), -1.f), 1.f) * sc);
    o.z = f2bf(fminf(fmaxf(rintf(v.z * inv), -1.f), 1.f) * sc);
    o.w = f2bf(fminf(fmaxf(rintf(v.w * inv), -1.f), 1.f) * sc);
    dst[i] = o;
  }
}

// ---------------- RMSNorm (f32 in -> bf16 out) ----------------
__global__ __launch_bounds__(256) void rmsnorm_k(
    const float* __restrict__ x, const float* __restrict__ wt,
    unsigned short* __restrict__ out) {
  const long long t = blockIdx.x;
  const float* xr = x + t * 2048;
  const int i0 = threadIdx.x * 8;
  float4 a = *(const float4*)(xr + i0);
  float4 b = *(const float4*)(xr + i0 + 4);
  float ss = a.x * a.x + a.y * a.y + a.z * a.z + a.w * a.w +
             b.x * b.x + b.y * b.y + b.z * b.z + b.w * b.w;
#pragma unroll
  for (int m = 1; m < 64; m <<= 1) ss += __shfl_xor(ss, m);
  __shared__ float red[4];
  if ((threadIdx.x & 63) == 0) red[threadIdx.x >> 6] = ss;
  __syncthreads();
  float tot = red[0] + red[1] + red[2] + red[3];
  float rs = rsqrtf(tot * (1.f / 2048.f) + 1e-5f);
  float4 wa = *(const float4*)(wt + i0);
  float4 wb = *(const float4*)(wt + i0 + 4);
  ushort4 o1, o2;
  o1.x = f2bf(a.x * wa.x * rs); o1.y = f2bf(a.y * wa.y * rs);
  o1.z = f2bf(a.z * wa.z * rs); o1.w = f2bf(a.w * wa.w * rs);
  o2.x = f2bf(b.x * wb.x * rs); o2.y = f2bf(b.y * wb.y * rs);
  o2.z = f2bf(b.z * wb.z * rs); o2.w = f2bf(b.w * wb.w * rs);
  *(ushort4*)(out + t * 2048 + i0) = o1;
  *(ushort4*)(out + t * 2048 + i0 + 4) = o2;
}

// ---- fused O-combine + RMSNorm(ln2), bf16 split-K partials ----
__global__ __launch_bounds__(256) void combine_rms(
    const float* __restrict__ ep, const unsigned short* __restrict__ p,
    const float* __restrict__ wt, float* __restrict__ hout,
    unsigned short* __restrict__ yout) {
  const long long t = blockIdx.x;
  const int i0 = threadIdx.x * 8;
  const long long base = t * 2048 + i0;
  float4 e1 = *(const float4*)(ep + base);
  float4 e2 = *(const float4*)(ep + base + 4);
  short8 pa = *(const short8*)(p + base);
  short8 pb = *(const short8*)(p + 8388608 + base);
  const float e[8] = {e1.x, e1.y, e1.z, e1.w, e2.x, e2.y, e2.z, e2.w};
  float h[8];
#pragma unroll
  for (int i = 0; i < 8; ++i)
    h[i] = e[i] + bf2f((unsigned short)pa[i]) + bf2f((unsigned short)pb[i]);
  float4 h1 = {h[0], h[1], h[2], h[3]};
  float4 h2 = {h[4], h[5], h[6], h[7]};
  *(float4*)(hout + base) = h1;
  *(float4*)(hout + base + 4) = h2;
  float ss = 0.f;
#pragma unroll
  for (int i = 0; i < 8; ++i) ss += h[i] * h[i];
#pragma unroll
  for (int m = 1; m < 64; m <<= 1) ss += __shfl_xor(ss, m);
  __shared__ float red[4];
  if ((threadIdx.x & 63) == 0) red[threadIdx.x >> 6] = ss;
  __syncthreads();
  const float tot = red[0] + red[1] + red[2] + red[3];
  const float rs = rsqrtf(tot * (1.f / 2048.f) + 1e-5f);
  float4 wa = *(const float4*)(wt + i0);
  float4 wb = *(const float4*)(wt + i0 + 4);
  ushort4 o1, o2;
  o1.x = f2bf(h[0] * wa.x * rs); o1.y = f2bf(h[1] * wa.y * rs);
  o1.z = f2bf(h[2] * wa.z * rs); o1.w = f2bf(h[3] * wa.w * rs);
  o2.x = f2bf(h[4] * wb.x * rs); o2.y = f2bf(h[5] * wb.y * rs);
  o2.z = f2bf(h[6] * wb.z * rs); o2.w = f2bf(h[7] * wb.w * rs);
  *(ushort4*)(yout + base) = o1;
  *(ushort4*)(yout + base + 4) = o2;
}

// ---- D-combine, bf16 partials: out = ep + p0 + p1 ----
__global__ __launch_bounds__(256) void combine2(
    const float* __restrict__ ep, const unsigned short* __restrict__ p,
    float* __restrict__ out) {
  const long long base = (long long)blockIdx.x * 2048 + threadIdx.x * 8;
  float4 e1 = *(const float4*)(ep + base);
  float4 e2 = *(const float4*)(ep + base + 4);
  short8 pa = *(const short8*)(p + base);
  short8 pb = *(const short8*)(p + 8388608 + base);
  float4 o1, o2;
  o1.x = e1.x + bf2f((unsigned short)pa[0]) + bf2f((unsigned short)pb[0]);
  o1.y = e1.y + bf2f((unsigned short)pa[1]) + bf2f((unsigned short)pb[1]);
  o1.z = e1.z + bf2f((unsigned short)pa[2]) + bf2f((unsigned short)pb[2]);
  o1.w = e1.w + bf2f((unsigned short)pa[3]) + bf2f((unsigned short)pb[3]);
  o2.x = e2.x + bf2f((unsigned short)pa[4]) + bf2f((unsigned short)pb[4]);
  o2.y = e2.y + bf2f((unsigned short)pa[5]) + bf2f((unsigned short)pb[5]);
  o2.z = e2.z + bf2f((unsigned short)pa[6]) + bf2f((unsigned short)pb[6]);
  o2.w = e2.w + bf2f((unsigned short)pa[7]) + bf2f((unsigned short)pb[7]);
  *(float4*)(out + base) = o1;
  *(float4*)(out + base + 4) = o2;
}

// ---------------- RoPE (q,k only; V handled by vtrans_k) ----------------
__global__ __launch_bounds__(256) void rope_k(
    const unsigned short* __restrict__ qkv, const float* __restrict__ cosT,
    const float* __restrict__ sinT, unsigned short* __restrict__ qr,
    unsigned short* __restrict__ kr) {
  const long long gid = (long long)blockIdx.x * 256 + threadIdx.x;
  const int t = (int)(gid >> 10);
  const int r = (int)(gid & 1023);
  const int h = r >> 6, d = r & 63;
  const int s = t & 2047;
  const unsigned short* row = qkv + (long long)t * 6144;
  const float c = cosT[s * 128 + d], sn = sinT[s * 128 + d];
  const int col = h * 128 + d;
  const float SC = 0.08838834764831845f;  // 1/sqrt(128)
  float q1 = bf2f(row[col]), q2 = bf2f(row[col + 64]);
  float k1 = bf2f(row[2048 + col]), k2 = bf2f(row[2048 + col + 64]);
  long long ob = (long long)t * 2048 + col;
  qr[ob] = f2bf((q1 * c - q2 * sn) * SC);
  qr[ob + 64] = f2bf((q2 * c + q1 * sn) * SC);
  kr[ob] = f2bf(k1 * c - k2 * sn);
  kr[ob + 64] = f2bf(k2 * c + k1 * sn);
}

// ---------------- V transpose via LDS tile (coalesced both sides) ----------
// grid (tTiles=32, dTiles=32, b=2); vt[b][d][t] = qkv[b,t][4096+d]
__global__ __launch_bounds__(256) void vtrans_k(
    const unsigned short* __restrict__ qkv, unsigned short* __restrict__ vt) {
  __shared__ unsigned short tile[64][66];
  const int tt = blockIdx.x << 6, dd = blockIdx.y << 6;
  const long long b = blockIdx.z;
  const int r0 = threadIdx.x >> 4, c0 = (threadIdx.x & 15) << 2;
#pragma unroll
  for (int i = 0; i < 4; ++i) {
    const int row = r0 + i * 16;
    ushort4 v = *(const ushort4*)&qkv[(b * 2048 + tt + row) * 6144 + 4096 + dd + c0];
    tile[row][c0] = v.x; tile[row][c0 + 1] = v.y;
    tile[row][c0 + 2] = v.z; tile[row][c0 + 3] = v.w;
  }
  __syncthreads();
#pragma unroll
  for (int i = 0; i < 4; ++i) {
    const int d = r0 + i * 16;
    ushort4 o;
    o.x = tile[c0][d]; o.y = tile[c0 + 1][d];
    o.z = tile[c0 + 2][d]; o.w = tile[c0 + 3][d];
    *(ushort4*)&vt[(b * 2048 + dd + d) * 2048 + tt + c0] = o;
  }
}

// ---------------- causal row softmax (single global read, regs) ----------------
__global__ __launch_bounds__(256) void softmax_causal(
    const float* __restrict__ scores, unsigned short* __restrict__ probs) {
  const int r = blockIdx.x;
  const int s = r & 2047;
  const float* src = scores + (long long)r * 2048;
  unsigned short* dst = probs + (long long)r * 2048;
  const int L = s + 1;
  const int j0 = threadIdx.x * 8;
  float4 a = *(const float4*)(src + j0);
  float4 b = *(const float4*)(src + j0 + 4);
  float v[8] = {a.x, a.y, a.z, a.w, b.x, b.y, b.z, b.w};
  float mx = -1e30f;
#pragma unroll
  for (int i = 0; i < 8; ++i) {
    if (j0 + i >= L) v[i] = -1e30f;
    mx = fmaxf(mx, v[i]);
  }
#pragma unroll
  for (int m = 1; m < 64; m <<= 1) mx = fmaxf(mx, __shfl_xor(mx, m));
  __shared__ float redM[4], redS[4];
  if ((threadIdx.x & 63) == 0) redM[threadIdx.x >> 6] = mx;
  __syncthreads();
  mx = fmaxf(fmaxf(redM[0], redM[1]), fmaxf(redM[2], redM[3]));
  float sum = 0.f;
#pragma unroll
  for (int i = 0; i < 8; ++i) {
    v[i] = (j0 + i < L) ? __expf(v[i] - mx) : 0.f;
    sum += v[i];
  }
#pragma unroll
  for (int m = 1; m < 64; m <<= 1) sum += __shfl_xor(sum, m);
  if ((threadIdx.x & 63) == 0) redS[threadIdx.x >> 6] = sum;
  __syncthreads();
  const float inv = 1.f / (redS[0] + redS[1] + redS[2] + redS[3]);
  ushort4 o1, o2;
  o1.x = f2bf(v[0] * inv); o1.y = f2bf(v[1] * inv);
  o1.z = f2bf(v[2] * inv); o1.w = f2bf(v[3] * inv);
  o2.x = f2bf(v[4] * inv); o2.y = f2bf(v[5] * inv);
  o2.z = f2bf(v[6] * inv); o2.w = f2bf(v[7] * inv);
  *(ushort4*)(dst + j0) = o1;
  *(ushort4*)(dst + j0 + 4) = o2;
}

// ------- 128^2 NT GEMM for attention QK/PV (4 blocks/CU, short K-path) -------
// EPI 0: bf16 out. 4: f32 raw. CAUSAL 1: skip n0 > m0+127. 2: K-limit (m0+128)/32.
template <int EPI, int CAUSAL>
__global__ __launch_bounds__(256) void gemm_nt(
    const unsigned short* __restrict__ A, const unsigned short* __restrict__ Bw,
    void* __restrict__ Cp, int M, int N, int K,
    long long sAz, long long sBz, long long sCz) {
  const long long m0 = (long long)blockIdx.y * 128;
  const long long n0 = (long long)blockIdx.x * 128;
  if (CAUSAL == 1 && n0 > m0 + 127) return;
  __shared__ __align__(16) unsigned short sA[2][128 * 32];
  __shared__ __align__(16) unsigned short sB[2][128 * 32];
  const int tid = threadIdx.x;
  const int w = tid >> 6, l = tid & 63;
  const long long z = blockIdx.z;
  A += z * sAz;
  Bw += z * sBz;
  const long long cofs = z * sCz;
  const int wr = w >> 1, wc = w & 1;
  const int lrow = l & 15, lk = (l >> 4) * 8;

  f32x4 acc[4][4] = {};
  int nk = K >> 5;
  if (CAUSAL == 2) nk = (int)((m0 + 128) >> 5);
  int cur = 0;

  auto stage = [&](int buf, int k0) {
#pragma unroll
    for (int i = 0; i < 2; ++i) {
      const int flat = (w * 2 + i) * 64 + l;
      const int row = flat >> 2;
      const int col = (flat & 3) * 8;
      gload_lds16(&A[(m0 + row) * K + k0 + col], (char*)&sA[buf][0] + (w * 2 + i) * 1024);
      gload_lds16(&Bw[(n0 + row) * K + k0 + col], (char*)&sB[buf][0] + (w * 2 + i) * 1024);
    }
  };

  stage(0, 0);
  __syncthreads();
  for (int kt = 0; kt < nk; ++kt) {
    if (kt + 1 < nk) stage(cur ^ 1, (kt + 1) << 5);
    short8 af[4], bfr[4];
#pragma unroll
    for (int m = 0; m < 4; ++m)
      af[m] = *(const short8*)&sA[cur][(wr * 64 + m * 16 + lrow) * 32 + lk];
#pragma unroll
    for (int n = 0; n < 4; ++n)
      bfr[n] = *(const short8*)&sB[cur][(wc * 64 + n * 16 + lrow) * 32 + lk];
#pragma unroll
    for (int m = 0; m < 4; ++m)
#pragma unroll
      for (int n = 0; n < 4; ++n)
        acc[m][n] = mfma16(af[m], bfr[n], acc[m][n]);
    __syncthreads();
    cur ^= 1;
  }

  const int orow = (l >> 4) * 4, ocol = l & 15;
#pragma unroll
  for (int m = 0; m < 4; ++m)
#pragma unroll
    for (int n = 0; n < 4; ++n)
#pragma unroll
      for (int r = 0; r < 4; ++r) {
        long long gr = m0 + wr * 64 + m * 16 + orow + r;
        long long gc = n0 + wc * 64 + n * 16 + ocol;
        long long idx = cofs + gr * N + gc;
        float v = acc[m][n][r];
        if (EPI == 0) ((unsigned short*)Cp)[idx] = f2bf(v);
        else ((float*)Cp)[idx] = v;
      }
}

// ---------------- 256^2 NT GEMM: pipelined, 4-unrolled (static slots) --------
// (unchanged from round 10 — see its header comment for the ledger)
template <int EPI, int CAUSAL>
__global__ __launch_bounds__(512, 2) void gemm256(
    const unsigned short* __restrict__ A, const unsigned short* __restrict__ Bw,
    void* __restrict__ Cp, const void* __restrict__ Ep,
    int N, int K, int nbx, int kLen, int ngTot,
    long long sAz, long long sBz, long long zCout) {
  __shared__ __align__(16) unsigned short lds[4 * 2 * 8192];  // 128KB
  __shared__ __align__(16) unsigned short ldsDummy[512];      // 1KB sink
  const int tid = threadIdx.x;
  const int wid = tid >> 6, l = tid & 63;
  const int wr = wid >> 2, wcn = wid & 3;

  const int nwg = gridDim.x;
  const int q8 = nwg >> 3;
  const int lin = (blockIdx.x & 7) * q8 + (blockIdx.x >> 3);
  const int t32 = lin >> 5, r32 = lin & 31;
  const int tpr = nbx >> 3;
  const int tm = t32 / tpr, tn = t32 - tm * tpr;
  const long long m0 = (long long)(tm * 4 + (r32 >> 3)) * 256;
  const long long n0 = (long long)(tn * 8 + (r32 & 7)) * 256;
  if (CAUSAL == 1 && n0 > m0) return;
  const int z = blockIdx.z;
  A += z * sAz;
  Bw += z * sBz;
  const long long kbase = (long long)z * kLen;
  const long long zofs = (long long)z * zCout;
  int ng = ngTot;
  if (CAUSAL == 2) {
    const int lim = (int)((m0 + 256) >> 5);
    ng = lim < ng ? lim : ng;
  }

  const int stRow = (l >> 2);
  const int stCol = (((l & 3) ^ ((l >> 3) & 3))) * 8;
  auto stage = [&](int chunk, int sslot) {
    if (chunk < ng) {
      char* base = (char*)lds + (sslot * 2) * 16384;
      const long long kcol = kbase + (long long)chunk * 32 + stCol;
#pragma unroll
      for (int i = 0; i < 2; ++i) {
        const int row = (wid * 2 + i) * 16 + stRow;
        gload_lds16(&A[(m0 + row) * K + kcol], base + (wid * 2 + i) * 1024);
        gload_lds16(&Bw[(n0 + row) * K + kcol],
                    base + 16384 + (wid * 2 + i) * 1024);
      }
    } else {
#pragma unroll
      for (int i = 0; i < 4; ++i) gload_lds16(&A[m0 * K], (char*)ldsDummy);
    }
  };

  const int ar = l & 15;
  const int rj = ((l >> 4) ^ ((l >> 1) & 3)) << 4;
  const int aoff = (wr * 128 + ar) * 64 + rj;
  const int boff = (wcn * 64 + ar) * 64 + rj;

  f32x4 acc[8][4] = {};
  short8 aX[4], bX[4], aY[4], bY[4];

  stage(0, 0); stage(1, 1); stage(2, 2);
  asm volatile("s_waitcnt vmcnt(4)" ::: "memory");
  __builtin_amdgcn_s_barrier();
#pragma unroll
  for (int m = 0; m < 4; ++m)
    aX[m] = *(const short8*)((const char*)lds + aoff + m * 1024);
#pragma unroll
  for (int n = 0; n < 4; ++n)
    bX[n] = *(const short8*)((const char*)lds + 16384 + boff + n * 1024);

#define CHUNK_BODY(SLOT, NSLOT, SYNC, cur03, curB, nxt03, nxtB, cc)            \
  {                                                                            \
    const char* sAc = (const char*)lds + (SLOT * 2) * 16384;                   \
    const char* sAn = (const char*)lds + (NSLOT * 2) * 16384;                  \
    const char* sBn = (const char*)lds + (NSLOT * 2 + 1) * 16384;              \
    short8 a47[4];                                                             \
    _Pragma("unroll") for (int m = 0; m < 4; ++m)                              \
        a47[m] = *(const short8*)(sAc + aoff + 4096 + m * 1024);               \
    stage((cc) + 3, (SLOT + 3) & 3);                                           \
    __builtin_amdgcn_s_setprio(1);                                             \
    _Pragma("unroll") for (int m = 0; m < 4; ++m)                              \
      _Pragma("unroll") for (int n = 0; n < 4; ++n)                            \
          acc[m][n] = mfma16(cur03[m], curB[n], acc[m][n]);                    \
    __builtin_amdgcn_s_setprio(0);                                             \
    if (SYNC) {                                                                \
      asm volatile("s_waitcnt vmcnt(4)" ::: "memory");                         \
      __builtin_amdgcn_s_barrier();                                            \
    }                                                                          \
    _Pragma("unroll") for (int m = 0; m < 4; ++m)                              \
        nxt03[m] = *(const short8*)(sAn + aoff + m * 1024);                    \
    _Pragma("unroll") for (int n = 0; n < 4; ++n)                              \
        nxtB[n] = *(const short8*)(sBn + boff + n * 1024);                     \
    __builtin_amdgcn_s_setprio(1);                                             \
    _Pragma("unroll") for (int m = 0; m < 4; ++m)                              \
      _Pragma("unroll") for (int n = 0; n < 4; ++n)                            \
          acc[m + 4][n] = mfma16(a47[m], curB[n], acc[m + 4][n]);              \
    __builtin_amdgcn_s_setprio(0);                                             \
  }

  for (int c = 0; c < ng; c += 4) {
    CHUNK_BODY(0, 1, false, aX, bX, aY, bY, c);
    CHUNK_BODY(1, 2, true, aY, bY, aX, bX, c + 1);
    CHUNK_BODY(2, 3, false, aX, bX, aY, bY, c + 2);
    CHUNK_BODY(3, 0, true, aY, bY, aX, bX, c + 3);
  }
#undef CHUNK_BODY
  asm volatile("s_waitcnt vmcnt(0)" ::: "memory");
  __builtin_amdgcn_s_barrier();

  const int orow = (l >> 4) * 4, ocol = l & 15;
#pragma unroll
  for (int m = 0; m < 8; ++m)
#pragma unroll
    for (int n = 0; n < 4; ++n)
#pragma unroll
      for (int r = 0; r < 4; ++r) {
        const long long gr = m0 + wr * 128 + m * 16 + orow + r;
        const long long gc = n0 + wcn * 64 + n * 16 + ocol;
        const long long idx = zofs + gr * N + gc;
        const float v = acc[m][n][r];
        if (EPI == 0) {
          ((unsigned short*)Cp)[idx] = f2bf(v);
        } else if (EPI == 2) {
          ((unsigned short*)Cp)[idx] = f2bf(bf2f(((const unsigned short*)Ep)[idx]) * v);
        } else {
          ((float*)Cp)[idx] = v;
        }
      }
}

extern "C" void kernel_launch(void* const* d_in, const int* in_sizes, int n_in,
                              void* d_out, int out_size, void* d_ws, size_t ws_size,
                              hipStream_t stream) {
  (void)in_sizes; (void)n_in; (void)out_size; (void)ws_size;
  const float* hidden = (const float*)d_in[0];
  const float* cosT = (const float*)d_in[2];
  const float* sinT = (const float*)d_in[3];
  const float* wq = (const float*)d_in[4];
  const float* wk = (const float*)d_in[5];
  const float* wv = (const float*)d_in[6];
  const float* wo = (const float*)d_in[7];
  const float* wg = (const float*)d_in[8];
  const float* wu = (const float*)d_in[9];
  const float* wd = (const float*)d_in[10];
  const float* ln1 = (const float*)d_in[11];
  const float* ln2 = (const float*)d_in[12];

  const size_t MB = 1ull << 20;
  char* ws = (char*)d_ws;
  unsigned short* xn    = (unsigned short*)(ws + 0);        // 16MB
  unsigned short* wqkvq = (unsigned short*)(ws + 16 * MB);  // 24MB
  unsigned short* qkv   = (unsigned short*)(ws + 40 * MB);  // 48MB
  unsigned short* qrb   = (unsigned short*)(ws + 88 * MB);  // 16MB
  unsigned short* krb   = (unsigned short*)(ws + 104 * MB); // 16MB
  unsigned short* vtb   = (unsigned short*)(ws + 120 * MB); // 16MB
  float*          scoresB = (float*)(ws + 0);               // 32MB alias
  unsigned short* probsB  = (unsigned short*)(ws + 40 * MB);// 16MB alias
  unsigned short* partb = (unsigned short*)(ws + 0);        // 32MB alias (bf16 x2)
  unsigned short* wgq   = (unsigned short*)(ws + 0);        // 32MB alias
  unsigned short* wuq   = (unsigned short*)(ws + 32 * MB);  // 32MB alias
  unsigned short* gbuf  = (unsigned short*)(ws + 64 * MB);  // 64MB alias
  unsigned short* attnb = (unsigned short*)(ws + 136 * MB); // 16MB
  unsigned short* woq   = (unsigned short*)(ws + 152 * MB); // 8MB
  float*          hbuf  = (float*)(ws + 160 * MB);          // 32MB
  unsigned short* ybuf  = (unsigned short*)(ws + 192 * MB); // 16MB
  unsigned short* gated = (unsigned short*)(ws + 208 * MB); // 64MB
  unsigned short* wdq   = (unsigned short*)(ws + 272 * MB); // 32MB
  float* wspart         = (float*)(ws + 304 * MB);          // 28KB
  float* scales         = (float*)(ws + 304 * MB + 32768);

  // --- scales ---
  MArgs am;
  am.src[0] = wq; am.src[1] = wk; am.src[2] = wv; am.src[3] = wo;
  am.src[4] = wg; am.src[5] = wu; am.src[6] = wd;
  am.n[0] = am.n[1] = am.n[2] = am.n[3] = 4194304;
  am.n[4] = am.n[5] = am.n[6] = 16777216;
  for (int i = 0; i < 7; ++i) { am.dst[i] = nullptr; am.sidx[i] = i; }
  absmean_partial_multi<<<dim3(1024, 7), 256, 0, stream>>>(am, wspart);
  absmean_final<<<7, 256, 0, stream>>>(wspart, scales);

  // --- early quantize: wq,wk,wv,wo,wd ---
  MArgs qe;
  qe.src[0] = wq; qe.dst[0] = wqkvq;            qe.n[0] = 4194304;  qe.sidx[0] = 0;
  qe.src[1] = wk; qe.dst[1] = wqkvq + 4194304;  qe.n[1] = 4194304;  qe.sidx[1] = 1;
  qe.src[2] = wv; qe.dst[2] = wqkvq + 8388608;  qe.n[2] = 4194304;  qe.sidx[2] = 2;
  qe.src[3] = wo; qe.dst[3] = woq;              qe.n[3] = 4194304;  qe.sidx[3] = 3;
  qe.src[4] = wd; qe.dst[4] = wdq;              qe.n[4] = 16777216; qe.sidx[4] = 6;
  qe.src[5] = wq; qe.dst[5] = nullptr; qe.n[5] = 0; qe.sidx[5] = 0;
  qe.src[6] = wq; qe.dst[6] = nullptr; qe.n[6] = 0; qe.sidx[6] = 0;
  quantize_multi<<<dim3(2048, 5), 256, 0, stream>>>(qe, scales);

  rmsnorm_k<<<4096, 256, 0, stream>>>(hidden, ln1, xn);

  // QKV: [4096x6144x2048], grid 384, 64 K-chunks
  gemm256<0, 0><<<dim3(384, 1, 1), 512, 0, stream>>>(
      xn, wqkvq, qkv, nullptr, 6144, 2048, 24, 2048, 64, 0, 0, 0);

  rope_k<<<16384, 256, 0, stream>>>(qkv, cosT, sinT, qrb, krb);
  vtrans_k<<<dim3(32, 32, 2), 256, 0, stream>>>(qkv, vtb);

  // attention on 128^2 gemm_nt (4 blocks/CU, short per-block K path)
  gemm_nt<4, 1><<<dim3(16, 16, 2), 256, 0, stream>>>(
      qrb, krb, scoresB, 2048, 2048, 2048, 4194304, 4194304, 4194304);
  softmax_causal<<<4096, 256, 0, stream>>>(scoresB, probsB);
  gemm_nt<0, 2><<<dim3(16, 16, 2), 256, 0, stream>>>(
      probsB, vtb, attnb, 2048, 2048, 2048, 4194304, 4194304, 4194304);

  // O-proj: split-K=2 bf16 partials -> fused combine + ln2 RMSNorm
  gemm256<0, 0><<<dim3(128, 1, 2), 512, 0, stream>>>(
      attnb, woq, partb, nullptr, 2048, 2048, 8, 1024, 32, 0, 0, 8388608);
  combine_rms<<<4096, 256, 0, stream>>>(hidden, partb, ln2, hbuf, ybuf);

  // late quantize: wg, wu
  MArgs ql;
  ql.src[0] = wg; ql.dst[0] = wgq; ql.n[0] = 16777216; ql.sidx[0] = 4;
  ql.src[1] = wu; ql.dst[1] = wuq; ql.n[1] = 16777216; ql.sidx[1] = 5;
  for (int i = 2; i < 7; ++i) { ql.src[i] = wg; ql.dst[i] = nullptr; ql.n[i] = 0; ql.sidx[i] = 0; }
  quantize_multi<<<dim3(2048, 2), 256, 0, stream>>>(ql, scales);

  // G, U: [4096x8192x2048], grid 512, 64 K-chunks
  gemm256<0, 0><<<dim3(512, 1, 1), 512, 0, stream>>>(
      ybuf, wgq, gbuf, nullptr, 8192, 2048, 32, 2048, 64, 0, 0, 0);
  gemm256<2, 0><<<dim3(512, 1, 1), 512, 0, stream>>>(
      ybuf, wuq, gated, gbuf, 8192, 2048, 32, 2048, 64, 0, 0, 0);

  // D: [4096x2048x8192] split-K=2 bf16 partials -> combine into d_out
  gemm256<0, 0><<<dim3(128, 1, 2), 512, 0, stream>>>(
      gated, wdq, partb, nullptr, 2048, 8192, 8, 4096, 128, 0, 0, 8388608);
  combine2<<<4096, 256, 0, stream>>>(hbuf, partb, (float*)d_out);
}